// Round 2
// baseline (758.283 us; speedup 1.0000x reference)
//
#include <hip/hip_runtime.h>
#include <hip/hip_bf16.h>
#include <cstdint>
#include <cstddef>

#define D_DIM 512
#define B_DIM 8
#define S_DIM 4096
#define M_DIM (B_DIM * S_DIM)   // 32768 tokens
#define CHUNK 64
#define NCHUNK (S_DIM / CHUNK)  // 64 chunks per batch
#define NSEG 8
#define CSEG (NCHUNK / NSEG)    // 8 chunks per segment
#define EPS_C 1e-6f

typedef __attribute__((ext_vector_type(8))) short bf16x8;
typedef __attribute__((ext_vector_type(4))) float f32x4;

__device__ __forceinline__ unsigned short f2bf(float f) {
  uint32_t u = __float_as_uint(f);
  u = (u + 0x7fffu + ((u >> 16) & 1u)) >> 16;   // RNE; inputs finite
  return (unsigned short)u;
}
__device__ __forceinline__ float bf2f(unsigned short s) { return __uint_as_float(((uint32_t)s) << 16); }

// ---------------- fp32 -> bf16 conversion ----------------
__global__ void cvt_f32_bf16(const float* __restrict__ in, unsigned short* __restrict__ out, int n4) {
  int i = blockIdx.x * blockDim.x + threadIdx.x;
  int stride = gridDim.x * blockDim.x;
  for (; i < n4; i += stride) {
    float4 f = ((const float4*)in)[i];
    ushort4 o;
    o.x = f2bf(f.x); o.y = f2bf(f.y); o.z = f2bf(f.z); o.w = f2bf(f.w);
    ((ushort4*)out)[i] = o;
  }
}

// ---------------- fused projection GEMM, async global->LDS staging (m97 pattern) ----
#define TM 128
#define TN 128
#define BK 32

__global__ __launch_bounds__(256) void proj_gemm(
    const unsigned short* __restrict__ Xb,
    const unsigned short* __restrict__ Wb,
    const float* __restrict__ bq, const float* __restrict__ bk,
    const float* __restrict__ bv, const float* __restrict__ ba,
    unsigned short* __restrict__ q_ws, unsigned short* __restrict__ k_ws,
    unsigned short* __restrict__ v_ws, unsigned short* __restrict__ g_ws) {
  __shared__ unsigned short As[TM * BK];   // 8 KB
  __shared__ unsigned short Bs[TN * BK];   // 8 KB

  const int proj = blockIdx.z;
  const unsigned short* W = Wb + (size_t)proj * D_DIM * D_DIM;
  const int m0 = blockIdx.x * TM;
  const int n0 = blockIdx.y * TN;
  const int tid = threadIdx.x;
  const int lane = tid & 63;
  const int wave = tid >> 6;
  const int wm = (wave & 1) * 64;
  const int wn = (wave >> 1) * 64;
  const int quad = lane >> 4;
  const int l16 = lane & 15;

  f32x4 acc[4][4];
#pragma unroll
  for (int i = 0; i < 4; ++i)
#pragma unroll
    for (int j = 0; j < 4; ++j) acc[i][j] = (f32x4){0.f, 0.f, 0.f, 0.f};

  const int rw = lane >> 2;           // row within 16-row wave slab
  const int kq = (lane & 3) * 8;      // k offset (8 shorts = 16B)

  for (int kc = 0; kc < D_DIM; kc += BK) {
    __syncthreads();  // previous chunk's fragment reads done
    {
      const unsigned short* gA0 = &Xb[(size_t)(m0 + wave * 16 + rw) * D_DIM + kc + kq];
      const unsigned short* gA1 = &Xb[(size_t)(m0 + 64 + wave * 16 + rw) * D_DIM + kc + kq];
      const unsigned short* gB0 = &W[(size_t)(n0 + wave * 16 + rw) * D_DIM + kc + kq];
      const unsigned short* gB1 = &W[(size_t)(n0 + 64 + wave * 16 + rw) * D_DIM + kc + kq];
      __builtin_amdgcn_global_load_lds(
          (const __attribute__((address_space(1))) void*)gA0,
          (__attribute__((address_space(3))) void*)&As[(wave * 16) * BK], 16, 0, 0);
      __builtin_amdgcn_global_load_lds(
          (const __attribute__((address_space(1))) void*)gA1,
          (__attribute__((address_space(3))) void*)&As[(64 + wave * 16) * BK], 16, 0, 0);
      __builtin_amdgcn_global_load_lds(
          (const __attribute__((address_space(1))) void*)gB0,
          (__attribute__((address_space(3))) void*)&Bs[(wave * 16) * BK], 16, 0, 0);
      __builtin_amdgcn_global_load_lds(
          (const __attribute__((address_space(1))) void*)gB1,
          (__attribute__((address_space(3))) void*)&Bs[(64 + wave * 16) * BK], 16, 0, 0);
    }
    __syncthreads();  // barrier drains vmcnt -> staged data visible

    bf16x8 afr[4], bfr[4];
#pragma unroll
    for (int im = 0; im < 4; ++im)
      afr[im] = *(const bf16x8*)&As[(wm + im * 16 + l16) * BK + quad * 8];
#pragma unroll
    for (int in = 0; in < 4; ++in)
      bfr[in] = *(const bf16x8*)&Bs[(wn + in * 16 + l16) * BK + quad * 8];
#pragma unroll
    for (int im = 0; im < 4; ++im)
#pragma unroll
      for (int in = 0; in < 4; ++in)
        acc[im][in] = __builtin_amdgcn_mfma_f32_16x16x32_bf16(afr[im], bfr[in], acc[im][in], 0, 0, 0);
  }

  const float* bias = (proj == 0) ? bq : (proj == 1) ? bk : (proj == 2) ? bv : ba;
#pragma unroll
  for (int in = 0; in < 4; ++in) {
    int nn = n0 + wn + in * 16 + l16;
    float bn = bias[nn];
#pragma unroll
    for (int im = 0; im < 4; ++im) {
      int mmb = m0 + wm + im * 16 + quad * 4;
#pragma unroll
      for (int vv = 0; vv < 4; ++vv) {
        float val = acc[im][in][vv] + bn;
        size_t idx = (size_t)(mmb + vv) * D_DIM + nn;
        if (proj == 0) {
          q_ws[idx] = f2bf(fmaxf(val, 0.f));
        } else if (proj == 1) {
          k_ws[idx] = f2bf(fmaxf(val, 0.f));
        } else if (proj == 2) {
          v_ws[idx] = f2bf(val);
        } else {
          g_ws[idx] = f2bf(val);   // raw preact; sigmoid in prep (fp32 cumprod there)
        }
      }
    }
  }
}

// ---------------- prep: cum-factorized operands (verified R3) ----------------
__global__ __launch_bounds__(512) void prep(
    const unsigned short* q, const unsigned short* k, const unsigned short* g,
    unsigned short* qt, unsigned short* kt, unsigned short* kh,
    float* Af, float* khs) {
  const int c = blockIdx.x, b = blockIdx.y;
  const int i = threadIdx.x;
  const size_t t0 = (size_t)b * S_DIM + (size_t)c * CHUNK;
  float cum = 1.f;
  for (int r = 0; r < CHUNK; ++r) {
    float gv = bf2f(g[(t0 + r) * D_DIM + i]);
    cum *= 1.f / (1.f + __expf(-gv));
  }
  const float cum63 = cum;
  const size_t cb = ((size_t)b * NCHUNK + c) * D_DIM;
  Af[cb + i] = cum63;
  cum = 1.f;
  float s = 0.f;
  for (int r = 0; r < CHUNK; ++r) {
    size_t idx = (t0 + r) * D_DIM + i;
    float gv = bf2f(g[idx]);
    cum *= 1.f / (1.f + __expf(-gv));   // identical op sequence to pass 1
    float qv = bf2f(q[idx]);
    float kv = bf2f(k[idx]);
    qt[idx] = f2bf(qv * cum);
    float inv = 1.f / cum;
    kt[idx] = f2bf(kv * inv);
    float khf = kv * (cum63 * inv);
    kh[idx] = f2bf(khf);
    s += khf;
  }
  khs[cb + i] = s;
}

// ---------------- per-chunk transpose [r][i] -> [i][r] (verified R3) ----------------
__global__ __launch_bounds__(256) void transpose_cd(
    const unsigned short* __restrict__ in, unsigned short* __restrict__ outT) {
  __shared__ unsigned short tile[CHUNK][264];
  const int c = blockIdx.x, b = blockIdx.y;
  const size_t base_in = ((size_t)b * S_DIM + (size_t)c * CHUNK) * D_DIM;
  const size_t base_out = ((size_t)b * NCHUNK + c) * (size_t)D_DIM * CHUNK;
  const int tid = threadIdx.x;
#pragma unroll
  for (int h = 0; h < 2; ++h) {
    if (h) __syncthreads();
#pragma unroll
    for (int it = 0; it < 8; ++it) {
      int flat = (it * 256 + tid) * 8;
      int row = flat >> 8;
      int col = flat & 255;
      *(uint4*)&tile[row][col] = *(const uint4*)&in[base_in + (size_t)row * D_DIM + h * 256 + col];
    }
    __syncthreads();
#pragma unroll
    for (int it = 0; it < 8; ++it) {
      int wq = it * 256 + tid;
      int i_loc = wq >> 3;
      int r0 = (wq & 7) * 8;
      ushort4 v0, v1;
      v0.x = tile[r0 + 0][i_loc]; v0.y = tile[r0 + 1][i_loc];
      v0.z = tile[r0 + 2][i_loc]; v0.w = tile[r0 + 3][i_loc];
      v1.x = tile[r0 + 4][i_loc]; v1.y = tile[r0 + 5][i_loc];
      v1.z = tile[r0 + 6][i_loc]; v1.w = tile[r0 + 7][i_loc];
      size_t o = base_out + (size_t)(h * 256 + i_loc) * CHUNK + r0;
      *(ushort4*)&outT[o] = v0;
      *(ushort4*)&outT[o + 4] = v1;
    }
  }
}

// ---------------- intra-chunk: P = mask(qt·kt^T), rowsums, numI = P·V (verified R3) ----
__global__ __launch_bounds__(256) void intra(
    const unsigned short* __restrict__ qt, const unsigned short* kt,
    const unsigned short* __restrict__ VT,
    unsigned short* numI, float* __restrict__ rs) {
  __shared__ unsigned short P_lds[CHUNK][CHUNK + 8];
  const int c = blockIdx.x, b = blockIdx.y;
  const size_t t0 = (size_t)b * S_DIM + (size_t)c * CHUNK;
  const int lane = threadIdx.x & 63, w = threadIdx.x >> 6;
  const int l16 = lane & 15, q4 = lane >> 4;

  f32x4 accP[4];
#pragma unroll
  for (int n = 0; n < 4; ++n) accP[n] = (f32x4){0.f, 0.f, 0.f, 0.f};
#pragma unroll
  for (int ks = 0; ks < 16; ++ks) {
    bf16x8 afr = *(const bf16x8*)&qt[(t0 + 16 * w + l16) * D_DIM + 32 * ks + 8 * q4];
#pragma unroll
    for (int n = 0; n < 4; ++n) {
      bf16x8 bfr = *(const bf16x8*)&kt[(t0 + 16 * n + l16) * D_DIM + 32 * ks + 8 * q4];
      accP[n] = __builtin_amdgcn_mfma_f32_16x16x32_bf16(afr, bfr, accP[n], 0, 0, 0);
    }
  }
  float rsum[4] = {0.f, 0.f, 0.f, 0.f};
#pragma unroll
  for (int n = 0; n < 4; ++n) {
    int m = 16 * n + l16;
#pragma unroll
    for (int vv = 0; vv < 4; ++vv) {
      int r = 16 * w + 4 * q4 + vv;
      float pv = (m <= r) ? accP[n][vv] : 0.f;
      rsum[vv] += pv;
      P_lds[r][m] = f2bf(pv);
    }
  }
#pragma unroll
  for (int msk = 1; msk < 16; msk <<= 1) {
#pragma unroll
    for (int vv = 0; vv < 4; ++vv) rsum[vv] += __shfl_xor(rsum[vv], msk, 64);
  }
  if (l16 == 0) {
#pragma unroll
    for (int vv = 0; vv < 4; ++vv) rs[t0 + 16 * w + 4 * q4 + vv] = rsum[vv];
  }
  __syncthreads();
  bf16x8 pa0 = *(const bf16x8*)&P_lds[16 * w + l16][8 * q4];
  bf16x8 pa1 = *(const bf16x8*)&P_lds[16 * w + l16][32 + 8 * q4];
  const size_t vtb = ((size_t)b * NCHUNK + c) * (size_t)D_DIM * CHUNK;
#pragma unroll 4
  for (int nt = 0; nt < 32; ++nt) {
    bf16x8 b0 = *(const bf16x8*)&VT[vtb + (size_t)(nt * 16 + l16) * CHUNK + 8 * q4];
    bf16x8 b1 = *(const bf16x8*)&VT[vtb + (size_t)(nt * 16 + l16) * CHUNK + 32 + 8 * q4];
    f32x4 acc = (f32x4){0.f, 0.f, 0.f, 0.f};
    acc = __builtin_amdgcn_mfma_f32_16x16x32_bf16(pa0, b0, acc, 0, 0, 0);
    acc = __builtin_amdgcn_mfma_f32_16x16x32_bf16(pa1, b1, acc, 0, 0, 0);
#pragma unroll
    for (int vv = 0; vv < 4; ++vv)
      numI[(t0 + 16 * w + 4 * q4 + vv) * D_DIM + nt * 16 + l16] = f2bf(acc[vv]);
  }
}

// ---------------- zscan: barrier-free z recurrence; also Pseg gate products ----------
__global__ __launch_bounds__(512) void zscan(
    const float* __restrict__ Af, const float* __restrict__ khs,
    float* __restrict__ zall, float* __restrict__ Pseg) {
  const int b = blockIdx.x;
  const int i = threadIdx.x;
  float z = 0.f, rp = 1.f;
  for (int c = 0; c < NCHUNK; ++c) {
    const size_t cb = ((size_t)b * NCHUNK + c) * D_DIM;
    zall[cb + i] = z;
    float af = Af[cb + i];
    z = fmaf(af, z, khs[cb + i]);
    rp *= af;
    if ((c & (CSEG - 1)) == CSEG - 1) {
      Pseg[((size_t)b * NSEG + (c / CSEG)) * D_DIM + i] = rp;
      rp = 1.f;
    }
  }
}

// ---------------- denk: fully parallel denominators (verified R4) ------------------
__global__ __launch_bounds__(512) void denk(
    const unsigned short* __restrict__ qt, const float* __restrict__ zall,
    float* rs_invden) {
  const int c = blockIdx.x, b = blockIdx.y;
  const int lane = threadIdx.x & 63, w = threadIdx.x >> 6;
  const size_t t0 = (size_t)b * S_DIM + (size_t)c * CHUNK;
  const size_t zb = ((size_t)b * NCHUNK + c) * D_DIM;
  float4 z0 = *(const float4*)&zall[zb + lane * 8];
  float4 z1 = *(const float4*)&zall[zb + lane * 8 + 4];
#pragma unroll
  for (int rr = 0; rr < 8; ++rr) {
    int r = 8 * w + rr;
    bf16x8 qv = *(const bf16x8*)&qt[(t0 + r) * D_DIM + lane * 8];
    float p = 0.f;
    p = fmaf(bf2f((unsigned short)qv[0]), z0.x, p);
    p = fmaf(bf2f((unsigned short)qv[1]), z0.y, p);
    p = fmaf(bf2f((unsigned short)qv[2]), z0.z, p);
    p = fmaf(bf2f((unsigned short)qv[3]), z0.w, p);
    p = fmaf(bf2f((unsigned short)qv[4]), z1.x, p);
    p = fmaf(bf2f((unsigned short)qv[5]), z1.y, p);
    p = fmaf(bf2f((unsigned short)qv[6]), z1.z, p);
    p = fmaf(bf2f((unsigned short)qv[7]), z1.w, p);
#pragma unroll
    for (int msk = 1; msk < 64; msk <<= 1) p += __shfl_xor(p, msk, 64);
    if (lane == 0) {
      float* iv = &rs_invden[t0 + r];
      *iv = 1.f / (p + *iv + EPS_C);
    }
  }
}

// ---------------- useg: per-segment state contribution, 32-j blocks ----------------
// grid (NSEG, 16 jt, B) -- s in blockIdx.x so the 16 jt blocks of one (s,b) have
// linear IDs differing by 8 -> same XCD under round-robin dispatch -> shared L2.
__global__ __launch_bounds__(512) void useg_k(
    const unsigned short* __restrict__ khT, const unsigned short* __restrict__ VT,
    const float* __restrict__ Af, unsigned short* __restrict__ U) {
  const int s = blockIdx.x, jt = blockIdx.y, b = blockIdx.z;
  const int lane = threadIdx.x & 63, w = threadIdx.x >> 6;
  const int l16 = lane & 15, q4 = lane >> 4;
  const int j0 = jt * 32, ib = 64 * w;

  f32x4 acc[4][2];
#pragma unroll
  for (int T = 0; T < 4; ++T)
#pragma unroll
    for (int h = 0; h < 2; ++h) acc[T][h] = (f32x4){0.f, 0.f, 0.f, 0.f};

  for (int cc = 0; cc < CSEG; ++cc) {
    const int c = s * CSEG + cc;
    const size_t cb = ((size_t)b * NCHUNK + c) * D_DIM;
    const size_t ob = cb * CHUNK;
#pragma unroll
    for (int T = 0; T < 4; ++T) {
      float4 af = *(const float4*)&Af[cb + ib + 16 * T + 4 * q4];
#pragma unroll
      for (int h = 0; h < 2; ++h) {
        acc[T][h][0] *= af.x; acc[T][h][1] *= af.y; acc[T][h][2] *= af.z; acc[T][h][3] *= af.w;
      }
    }
    bf16x8 bv00 = *(const bf16x8*)&VT[ob + (size_t)(j0 + l16) * CHUNK + 8 * q4];
    bf16x8 bv01 = *(const bf16x8*)&VT[ob + (size_t)(j0 + l16) * CHUNK + 32 + 8 * q4];
    bf16x8 bv10 = *(const bf16x8*)&VT[ob + (size_t)(j0 + 16 + l16) * CHUNK + 8 * q4];
    bf16x8 bv11 = *(const bf16x8*)&VT[ob + (size_t)(j0 + 16 + l16) * CHUNK + 32 + 8 * q4];
#pragma unroll
    for (int T = 0; T < 4; ++T) {
      bf16x8 a0 = *(const bf16x8*)&khT[ob + (size_t)(ib + 16 * T + l16) * CHUNK + 8 * q4];
      bf16x8 a1 = *(const bf16x8*)&khT[ob + (size_t)(ib + 16 * T + l16) * CHUNK + 32 + 8 * q4];
      acc[T][0] = __builtin_amdgcn_mfma_f32_16x16x32_bf16(a0, bv00, acc[T][0], 0, 0, 0);
      acc[T][0] = __builtin_amdgcn_mfma_f32_16x16x32_bf16(a1, bv01, acc[T][0], 0, 0, 0);
      acc[T][1] = __builtin_amdgcn_mfma_f32_16x16x32_bf16(a0, bv10, acc[T][1], 0, 0, 0);
      acc[T][1] = __builtin_amdgcn_mfma_f32_16x16x32_bf16(a1, bv11, acc[T][1], 0, 0, 0);
    }
  }
  const size_t ub = ((size_t)b * NSEG + s) * D_DIM;
#pragma unroll
  for (int T = 0; T < 4; ++T)
#pragma unroll
    for (int h = 0; h < 2; ++h) {
      uint2 pk;
      pk.x = (uint32_t)f2bf(acc[T][h][0]) | ((uint32_t)f2bf(acc[T][h][1]) << 16);
      pk.y = (uint32_t)f2bf(acc[T][h][2]) | ((uint32_t)f2bf(acc[T][h][3]) << 16);
      *(uint2*)&U[(ub + j0 + 16 * h + l16) * (size_t)D_DIM + ib + 16 * T + 4 * q4] = pk;
    }
}

// ---------------- sscan: in-place prefix over segments: U[s] -> Sin[s] -------------
// Sin[s] = fold_{sp<s} (acc = Pseg[sp] (*) acc + U[sp]); Sin[0] = 0.
// One thread owns (b, j, 8 consecutive i) for all s -> in-place safe, coalesced.
__global__ __launch_bounds__(256) void sscan(
    const float* __restrict__ Pseg, unsigned short* __restrict__ U) {
  const int b = blockIdx.y;
  const int flat = blockIdx.x * 256 + threadIdx.x;   // 0 .. 32767
  const int j = flat >> 6;
  const int i0 = (flat & 63) * 8;
  float acc[8];
#pragma unroll
  for (int t = 0; t < 8; ++t) acc[t] = 0.f;
  for (int s = 0; s < NSEG; ++s) {
    const size_t pb = ((size_t)b * NSEG + s) * D_DIM;
    unsigned short* up = &U[(pb + j) * (size_t)D_DIM + i0];
    uint4 u = *(const uint4*)up;
    float4 p0 = *(const float4*)&Pseg[pb + i0];
    float4 p1 = *(const float4*)&Pseg[pb + i0 + 4];
    float uv[8];
    uv[0] = bf2f((unsigned short)(u.x & 0xffff)); uv[1] = bf2f((unsigned short)(u.x >> 16));
    uv[2] = bf2f((unsigned short)(u.y & 0xffff)); uv[3] = bf2f((unsigned short)(u.y >> 16));
    uv[4] = bf2f((unsigned short)(u.z & 0xffff)); uv[5] = bf2f((unsigned short)(u.z >> 16));
    uv[6] = bf2f((unsigned short)(u.w & 0xffff)); uv[7] = bf2f((unsigned short)(u.w >> 16));
    uint4 o;
    o.x = (uint32_t)f2bf(acc[0]) | ((uint32_t)f2bf(acc[1]) << 16);
    o.y = (uint32_t)f2bf(acc[2]) | ((uint32_t)f2bf(acc[3]) << 16);
    o.z = (uint32_t)f2bf(acc[4]) | ((uint32_t)f2bf(acc[5]) << 16);
    o.w = (uint32_t)f2bf(acc[6]) | ((uint32_t)f2bf(acc[7]) << 16);
    *(uint4*)up = o;
    acc[0] = fmaf(p0.x, acc[0], uv[0]);
    acc[1] = fmaf(p0.y, acc[1], uv[1]);
    acc[2] = fmaf(p0.z, acc[2], uv[2]);
    acc[3] = fmaf(p0.w, acc[3], uv[3]);
    acc[4] = fmaf(p1.x, acc[4], uv[4]);
    acc[5] = fmaf(p1.y, acc[5], uv[5]);
    acc[6] = fmaf(p1.z, acc[6], uv[6]);
    acc[7] = fmaf(p1.w, acc[7], uv[7]);
  }
}

// ---------------- scan2: segment replay, 32-j blocks -------------------------------
// grid (NSEG, 16 jt, B) -- see useg_k comment (XCD L2 sharing).
// Prefix fold replaced by a single Sin load (uniform blocks, no tail imbalance).
__global__ __launch_bounds__(512) void scan2(
    const unsigned short* __restrict__ qt, const unsigned short* __restrict__ khT,
    const unsigned short* __restrict__ VT, const float* __restrict__ Af,
    const unsigned short* __restrict__ Sin,
    const unsigned short* __restrict__ numI, const float* __restrict__ invden,
    float* __restrict__ out) {
  __shared__ unsigned short STj[32][520];  // S^T: [j_local][i] bf16, 33.3 KB
  const int s = blockIdx.x, jt = blockIdx.y, b = blockIdx.z;
  const int lane = threadIdx.x & 63, w = threadIdx.x >> 6;   // wave-uniform w
  const int l16 = lane & 15, q4 = lane >> 4;
  const int j0 = jt * 32;
  const bool is_state = (w >= 4);
  const int wv = w - 4;
  const int ib = 128 * wv;

  f32x4 acc[8][2];
#pragma unroll
  for (int T = 0; T < 8; ++T)
#pragma unroll
    for (int h = 0; h < 2; ++h) acc[T][h] = (f32x4){0.f, 0.f, 0.f, 0.f};

  if (is_state) {
    // initial state for this segment, precomputed by sscan (uniform, single load)
    const size_t pb = ((size_t)b * NSEG + s) * D_DIM;
#pragma unroll
    for (int T = 0; T < 8; ++T)
#pragma unroll
      for (int h = 0; h < 2; ++h) {
        uint2 uu = *(const uint2*)&Sin[(pb + j0 + 16 * h + l16) * (size_t)D_DIM + ib + 16 * T + 4 * q4];
        acc[T][h][0] = bf2f((unsigned short)(uu.x & 0xffff));
        acc[T][h][1] = bf2f((unsigned short)(uu.x >> 16));
        acc[T][h][2] = bf2f((unsigned short)(uu.y & 0xffff));
        acc[T][h][3] = bf2f((unsigned short)(uu.y >> 16));
      }
  }

  for (int cc = 0; cc < CSEG; ++cc) {
    const int c = s * CSEG + cc;
    if (is_state) {
#pragma unroll
      for (int T = 0; T < 8; ++T)
#pragma unroll
        for (int h = 0; h < 2; ++h) {
          uint2 pk;
          pk.x = (uint32_t)f2bf(acc[T][h][0]) | ((uint32_t)f2bf(acc[T][h][1]) << 16);
          pk.y = (uint32_t)f2bf(acc[T][h][2]) | ((uint32_t)f2bf(acc[T][h][3]) << 16);
          *(uint2*)&STj[16 * h + l16][ib + 16 * T + 4 * q4] = pk;
        }
    }
    __syncthreads();
    const size_t cb = ((size_t)b * NCHUNK + c) * D_DIM;
    const size_t t0 = (size_t)b * S_DIM + (size_t)c * CHUNK;
    if (is_state) {
#pragma unroll
      for (int T = 0; T < 8; ++T) {
        float4 af = *(const float4*)&Af[cb + ib + 16 * T + 4 * q4];
#pragma unroll
        for (int h = 0; h < 2; ++h) {
          acc[T][h][0] *= af.x; acc[T][h][1] *= af.y; acc[T][h][2] *= af.z; acc[T][h][3] *= af.w;
        }
      }
      const size_t ob = cb * CHUNK;
      bf16x8 bv00 = *(const bf16x8*)&VT[ob + (size_t)(j0 + l16) * CHUNK + 8 * q4];
      bf16x8 bv01 = *(const bf16x8*)&VT[ob + (size_t)(j0 + l16) * CHUNK + 32 + 8 * q4];
      bf16x8 bv10 = *(const bf16x8*)&VT[ob + (size_t)(j0 + 16 + l16) * CHUNK + 8 * q4];
      bf16x8 bv11 = *(const bf16x8*)&VT[ob + (size_t)(j0 + 16 + l16) * CHUNK + 32 + 8 * q4];
#pragma unroll
      for (int T = 0; T < 8; ++T) {
        bf16x8 a0 = *(const bf16x8*)&khT[ob + (size_t)(ib + 16 * T + l16) * CHUNK + 8 * q4];
        bf16x8 a1 = *(const bf16x8*)&khT[ob + (size_t)(ib + 16 * T + l16) * CHUNK + 32 + 8 * q4];
        acc[T][0] = __builtin_amdgcn_mfma_f32_16x16x32_bf16(a0, bv00, acc[T][0], 0, 0, 0);
        acc[T][0] = __builtin_amdgcn_mfma_f32_16x16x32_bf16(a1, bv01, acc[T][0], 0, 0, 0);
        acc[T][1] = __builtin_amdgcn_mfma_f32_16x16x32_bf16(a0, bv10, acc[T][1], 0, 0, 0);
        acc[T][1] = __builtin_amdgcn_mfma_f32_16x16x32_bf16(a1, bv11, acc[T][1], 0, 0, 0);
      }
    } else {
      f32x4 accO0 = (f32x4){0.f, 0.f, 0.f, 0.f};
      f32x4 accO1 = (f32x4){0.f, 0.f, 0.f, 0.f};
#pragma unroll
      for (int ks = 0; ks < 16; ++ks) {
        bf16x8 afr = *(const bf16x8*)&qt[(t0 + 16 * w + l16) * D_DIM + 32 * ks + 8 * q4];
        bf16x8 bfr0 = *(const bf16x8*)&STj[l16][32 * ks + 8 * q4];
        bf16x8 bfr1 = *(const bf16x8*)&STj[16 + l16][32 * ks + 8 * q4];
        accO0 = __builtin_amdgcn_mfma_f32_16x16x32_bf16(afr, bfr0, accO0, 0, 0, 0);
        accO1 = __builtin_amdgcn_mfma_f32_16x16x32_bf16(afr, bfr1, accO1, 0, 0, 0);
      }
#pragma unroll
      for (int vv = 0; vv < 4; ++vv) {
        size_t t = t0 + 16 * w + 4 * q4 + vv;
        float idv = invden[t];
        float nI0 = bf2f(numI[t * D_DIM + j0 + l16]);
        float nI1 = bf2f(numI[t * D_DIM + j0 + 16 + l16]);
        out[t * D_DIM + j0 + l16] = (accO0[vv] + nI0) * idv;
        out[t * D_DIM + j0 + 16 + l16] = (accO1[vv] + nI1) * idv;
      }
    }
    __syncthreads();
  }
}

// ---------------- launch ----------------
extern "C" void kernel_launch(void* const* d_in, const int* in_sizes, int n_in,
                              void* d_out, int out_size, void* d_ws, size_t ws_size,
                              hipStream_t stream) {
  const float* x  = (const float*)d_in[0];
  const float* Wq = (const float*)d_in[1];
  const float* bq = (const float*)d_in[2];
  const float* Wk = (const float*)d_in[3];
  const float* bk = (const float*)d_in[4];
  const float* Wv = (const float*)d_in[5];
  const float* bv = (const float*)d_in[6];
  const float* Wa = (const float*)d_in[7];
  const float* ba = (const float*)d_in[8];
  float* out = (float*)d_out;

  // Workspace layout identical to R3/R4 (proven): ~172 MB.
  const size_t MD2 = (size_t)M_DIM * D_DIM * 2;
  uint8_t* w = (uint8_t*)d_ws;
  unsigned short* xb   = (unsigned short*)w; w += MD2;
  unsigned short* wb   = (unsigned short*)w; w += (size_t)4 * D_DIM * D_DIM * 2;  // 2 MB
  unsigned short* q_ws = (unsigned short*)w; w += MD2;
  unsigned short* k_ws = (unsigned short*)w; w += MD2;
  unsigned short* v_ws = (unsigned short*)w; w += MD2;
  unsigned short* g_ws = (unsigned short*)w; w += MD2;
  float* Af     = (float*)w; w += (size_t)B_DIM * NCHUNK * D_DIM * 4;  // 1 MB
  float* khs    = (float*)w; w += (size_t)B_DIM * NCHUNK * D_DIM * 4;  // 1 MB
  float* invden = (float*)w; w += (size_t)M_DIM * 4;                   // 128 KB

  unsigned short* qt   = xb;     // xb dead after proj_gemm
  unsigned short* kt   = q_ws;   // same-index overwrite inside prep
  unsigned short* kh   = k_ws;   // same-index overwrite inside prep
  unsigned short* VT   = g_ws;   // g dead after prep
  unsigned short* khT  = v_ws;   // v dead after its transpose
  unsigned short* numI = q_ws;   // kt dead after intra's P-phase
  unsigned short* U    = k_ws;   // kh dead after khT transpose; NSEG*B*512*512*2 == MD2 exactly
  float* zall = (float*)wb;                          // wb dead after proj; 1 MB
  float* Pseg = (float*)((uint8_t*)wb + (1 << 20));  // 128 KB

  cvt_f32_bf16<<<1024, 256, 0, stream>>>(x, xb, M_DIM * D_DIM / 4);
  cvt_f32_bf16<<<128, 256, 0, stream>>>(Wq, wb + 0 * D_DIM * D_DIM, D_DIM * D_DIM / 4);
  cvt_f32_bf16<<<128, 256, 0, stream>>>(Wk, wb + 1 * D_DIM * D_DIM, D_DIM * D_DIM / 4);
  cvt_f32_bf16<<<128, 256, 0, stream>>>(Wv, wb + 2 * D_DIM * D_DIM, D_DIM * D_DIM / 4);
  cvt_f32_bf16<<<128, 256, 0, stream>>>(Wa, wb + 3 * D_DIM * D_DIM, D_DIM * D_DIM / 4);

  proj_gemm<<<dim3(M_DIM / TM, D_DIM / TN, 4), 256, 0, stream>>>(
      xb, wb, bq, bk, bv, ba, q_ws, k_ws, v_ws, g_ws);

  prep<<<dim3(NCHUNK, B_DIM), 512, 0, stream>>>(q_ws, k_ws, g_ws, qt, kt, kh, Af, khs);
  transpose_cd<<<dim3(NCHUNK, B_DIM), 256, 0, stream>>>(v_ws, VT);
  transpose_cd<<<dim3(NCHUNK, B_DIM), 256, 0, stream>>>(kh, khT);
  zscan<<<B_DIM, 512, 0, stream>>>(Af, khs, zall, Pseg);
  intra<<<dim3(NCHUNK, B_DIM), 256, 0, stream>>>(qt, kt, VT, numI, invden);
  denk<<<dim3(NCHUNK, B_DIM), 512, 0, stream>>>(qt, zall, invden);
  useg_k<<<dim3(NSEG, 16, B_DIM), 512, 0, stream>>>(khT, VT, Af, U);
  sscan<<<dim3(128, B_DIM), 256, 0, stream>>>(Pseg, U);   // U -> Sin in place
  scan2<<<dim3(NSEG, 16, B_DIM), 512, 0, stream>>>(qt, khT, VT, Af, U, numI, invden, out);
}

// Round 3
// 568.662 us; speedup vs baseline: 1.3334x; 1.3334x over previous
//
#include <hip/hip_runtime.h>
#include <hip/hip_bf16.h>
#include <cstdint>
#include <cstddef>

#define D_DIM 512
#define B_DIM 8
#define S_DIM 4096
#define M_DIM (B_DIM * S_DIM)   // 32768 tokens
#define CHUNK 64
#define NCHUNK (S_DIM / CHUNK)  // 64 chunks per batch
#define NSEG 8
#define CSEG (NCHUNK / NSEG)    // 8 chunks per segment
#define EPS_C 1e-6f

typedef __attribute__((ext_vector_type(8))) short bf16x8;
typedef __attribute__((ext_vector_type(4))) float f32x4;

__device__ __forceinline__ unsigned short f2bf(float f) {
  uint32_t u = __float_as_uint(f);
  u = (u + 0x7fffu + ((u >> 16) & 1u)) >> 16;   // RNE; inputs finite
  return (unsigned short)u;
}
__device__ __forceinline__ float bf2f(unsigned short s) { return __uint_as_float(((uint32_t)s) << 16); }

// ---------------- fp32 -> bf16 conversion ----------------
__global__ void cvt_f32_bf16(const float* __restrict__ in, unsigned short* __restrict__ out, int n4) {
  int i = blockIdx.x * blockDim.x + threadIdx.x;
  int stride = gridDim.x * blockDim.x;
  for (; i < n4; i += stride) {
    float4 f = ((const float4*)in)[i];
    ushort4 o;
    o.x = f2bf(f.x); o.y = f2bf(f.y); o.z = f2bf(f.z); o.w = f2bf(f.w);
    ((ushort4*)out)[i] = o;
  }
}

// ---------------- fused projection GEMM, async global->LDS staging (m97 pattern) ----
#define TM 128
#define TN 128
#define BK 32

__global__ __launch_bounds__(256) void proj_gemm(
    const unsigned short* __restrict__ Xb,
    const unsigned short* __restrict__ Wb,
    const float* __restrict__ bq, const float* __restrict__ bk,
    const float* __restrict__ bv, const float* __restrict__ ba,
    unsigned short* __restrict__ q_ws, unsigned short* __restrict__ k_ws,
    unsigned short* __restrict__ v_ws, unsigned short* __restrict__ g_ws) {
  __shared__ unsigned short As[TM * BK];   // 8 KB
  __shared__ unsigned short Bs[TN * BK];   // 8 KB

  const int proj = blockIdx.z;
  const unsigned short* W = Wb + (size_t)proj * D_DIM * D_DIM;
  const int m0 = blockIdx.x * TM;
  const int n0 = blockIdx.y * TN;
  const int tid = threadIdx.x;
  const int lane = tid & 63;
  const int wave = tid >> 6;
  const int wm = (wave & 1) * 64;
  const int wn = (wave >> 1) * 64;
  const int quad = lane >> 4;
  const int l16 = lane & 15;

  f32x4 acc[4][4];
#pragma unroll
  for (int i = 0; i < 4; ++i)
#pragma unroll
    for (int j = 0; j < 4; ++j) acc[i][j] = (f32x4){0.f, 0.f, 0.f, 0.f};

  const int rw = lane >> 2;           // row within 16-row wave slab
  const int kq = (lane & 3) * 8;      // k offset (8 shorts = 16B)

  for (int kc = 0; kc < D_DIM; kc += BK) {
    __syncthreads();  // previous chunk's fragment reads done
    {
      const unsigned short* gA0 = &Xb[(size_t)(m0 + wave * 16 + rw) * D_DIM + kc + kq];
      const unsigned short* gA1 = &Xb[(size_t)(m0 + 64 + wave * 16 + rw) * D_DIM + kc + kq];
      const unsigned short* gB0 = &W[(size_t)(n0 + wave * 16 + rw) * D_DIM + kc + kq];
      const unsigned short* gB1 = &W[(size_t)(n0 + 64 + wave * 16 + rw) * D_DIM + kc + kq];
      __builtin_amdgcn_global_load_lds(
          (const __attribute__((address_space(1))) void*)gA0,
          (__attribute__((address_space(3))) void*)&As[(wave * 16) * BK], 16, 0, 0);
      __builtin_amdgcn_global_load_lds(
          (const __attribute__((address_space(1))) void*)gA1,
          (__attribute__((address_space(3))) void*)&As[(64 + wave * 16) * BK], 16, 0, 0);
      __builtin_amdgcn_global_load_lds(
          (const __attribute__((address_space(1))) void*)gB0,
          (__attribute__((address_space(3))) void*)&Bs[(wave * 16) * BK], 16, 0, 0);
      __builtin_amdgcn_global_load_lds(
          (const __attribute__((address_space(1))) void*)gB1,
          (__attribute__((address_space(3))) void*)&Bs[(64 + wave * 16) * BK], 16, 0, 0);
    }
    __syncthreads();  // barrier drains vmcnt -> staged data visible

    bf16x8 afr[4], bfr[4];
#pragma unroll
    for (int im = 0; im < 4; ++im)
      afr[im] = *(const bf16x8*)&As[(wm + im * 16 + l16) * BK + quad * 8];
#pragma unroll
    for (int in = 0; in < 4; ++in)
      bfr[in] = *(const bf16x8*)&Bs[(wn + in * 16 + l16) * BK + quad * 8];
#pragma unroll
    for (int im = 0; im < 4; ++im)
#pragma unroll
      for (int in = 0; in < 4; ++in)
        acc[im][in] = __builtin_amdgcn_mfma_f32_16x16x32_bf16(afr[im], bfr[in], acc[im][in], 0, 0, 0);
  }

  const float* bias = (proj == 0) ? bq : (proj == 1) ? bk : (proj == 2) ? bv : ba;
#pragma unroll
  for (int in = 0; in < 4; ++in) {
    int nn = n0 + wn + in * 16 + l16;
    float bn = bias[nn];
#pragma unroll
    for (int im = 0; im < 4; ++im) {
      int mmb = m0 + wm + im * 16 + quad * 4;
#pragma unroll
      for (int vv = 0; vv < 4; ++vv) {
        float val = acc[im][in][vv] + bn;
        size_t idx = (size_t)(mmb + vv) * D_DIM + nn;
        if (proj == 0) {
          q_ws[idx] = f2bf(fmaxf(val, 0.f));
        } else if (proj == 1) {
          k_ws[idx] = f2bf(fmaxf(val, 0.f));
        } else if (proj == 2) {
          v_ws[idx] = f2bf(val);
        } else {
          g_ws[idx] = f2bf(val);   // raw preact; sigmoid in prep (fp32 cumprod there)
        }
      }
    }
  }
}

// ---------------- prep: cum-factorized operands (verified R3) ----------------
__global__ __launch_bounds__(512) void prep(
    const unsigned short* q, const unsigned short* k, const unsigned short* g,
    unsigned short* qt, unsigned short* kt, unsigned short* kh,
    float* Af, float* khs) {
  const int c = blockIdx.x, b = blockIdx.y;
  const int i = threadIdx.x;
  const size_t t0 = (size_t)b * S_DIM + (size_t)c * CHUNK;
  float cum = 1.f;
  for (int r = 0; r < CHUNK; ++r) {
    float gv = bf2f(g[(t0 + r) * D_DIM + i]);
    cum *= 1.f / (1.f + __expf(-gv));
  }
  const float cum63 = cum;
  const size_t cb = ((size_t)b * NCHUNK + c) * D_DIM;
  Af[cb + i] = cum63;
  cum = 1.f;
  float s = 0.f;
  for (int r = 0; r < CHUNK; ++r) {
    size_t idx = (t0 + r) * D_DIM + i;
    float gv = bf2f(g[idx]);
    cum *= 1.f / (1.f + __expf(-gv));   // identical op sequence to pass 1
    float qv = bf2f(q[idx]);
    float kv = bf2f(k[idx]);
    qt[idx] = f2bf(qv * cum);
    float inv = 1.f / cum;
    kt[idx] = f2bf(kv * inv);
    float khf = kv * (cum63 * inv);
    kh[idx] = f2bf(khf);
    s += khf;
  }
  khs[cb + i] = s;
}

// ---------------- per-chunk transpose [r][i] -> [i][r] (verified R3) ----------------
__global__ __launch_bounds__(256) void transpose_cd(
    const unsigned short* __restrict__ in, unsigned short* __restrict__ outT) {
  __shared__ unsigned short tile[CHUNK][264];
  const int c = blockIdx.x, b = blockIdx.y;
  const size_t base_in = ((size_t)b * S_DIM + (size_t)c * CHUNK) * D_DIM;
  const size_t base_out = ((size_t)b * NCHUNK + c) * (size_t)D_DIM * CHUNK;
  const int tid = threadIdx.x;
#pragma unroll
  for (int h = 0; h < 2; ++h) {
    if (h) __syncthreads();
#pragma unroll
    for (int it = 0; it < 8; ++it) {
      int flat = (it * 256 + tid) * 8;
      int row = flat >> 8;
      int col = flat & 255;
      *(uint4*)&tile[row][col] = *(const uint4*)&in[base_in + (size_t)row * D_DIM + h * 256 + col];
    }
    __syncthreads();
#pragma unroll
    for (int it = 0; it < 8; ++it) {
      int wq = it * 256 + tid;
      int i_loc = wq >> 3;
      int r0 = (wq & 7) * 8;
      ushort4 v0, v1;
      v0.x = tile[r0 + 0][i_loc]; v0.y = tile[r0 + 1][i_loc];
      v0.z = tile[r0 + 2][i_loc]; v0.w = tile[r0 + 3][i_loc];
      v1.x = tile[r0 + 4][i_loc]; v1.y = tile[r0 + 5][i_loc];
      v1.z = tile[r0 + 6][i_loc]; v1.w = tile[r0 + 7][i_loc];
      size_t o = base_out + (size_t)(h * 256 + i_loc) * CHUNK + r0;
      *(ushort4*)&outT[o] = v0;
      *(ushort4*)&outT[o + 4] = v1;
    }
  }
}

// ---------------- intra-chunk: P = mask(qt·kt^T), rowsums, numI = P·V (verified R3) ----
__global__ __launch_bounds__(256) void intra(
    const unsigned short* __restrict__ qt, const unsigned short* kt,
    const unsigned short* __restrict__ VT,
    unsigned short* numI, float* __restrict__ rs) {
  __shared__ unsigned short P_lds[CHUNK][CHUNK + 8];
  const int c = blockIdx.x, b = blockIdx.y;
  const size_t t0 = (size_t)b * S_DIM + (size_t)c * CHUNK;
  const int lane = threadIdx.x & 63, w = threadIdx.x >> 6;
  const int l16 = lane & 15, q4 = lane >> 4;

  f32x4 accP[4];
#pragma unroll
  for (int n = 0; n < 4; ++n) accP[n] = (f32x4){0.f, 0.f, 0.f, 0.f};
#pragma unroll
  for (int ks = 0; ks < 16; ++ks) {
    bf16x8 afr = *(const bf16x8*)&qt[(t0 + 16 * w + l16) * D_DIM + 32 * ks + 8 * q4];
#pragma unroll
    for (int n = 0; n < 4; ++n) {
      bf16x8 bfr = *(const bf16x8*)&kt[(t0 + 16 * n + l16) * D_DIM + 32 * ks + 8 * q4];
      accP[n] = __builtin_amdgcn_mfma_f32_16x16x32_bf16(afr, bfr, accP[n], 0, 0, 0);
    }
  }
  float rsum[4] = {0.f, 0.f, 0.f, 0.f};
#pragma unroll
  for (int n = 0; n < 4; ++n) {
    int m = 16 * n + l16;
#pragma unroll
    for (int vv = 0; vv < 4; ++vv) {
      int r = 16 * w + 4 * q4 + vv;
      float pv = (m <= r) ? accP[n][vv] : 0.f;
      rsum[vv] += pv;
      P_lds[r][m] = f2bf(pv);
    }
  }
#pragma unroll
  for (int msk = 1; msk < 16; msk <<= 1) {
#pragma unroll
    for (int vv = 0; vv < 4; ++vv) rsum[vv] += __shfl_xor(rsum[vv], msk, 64);
  }
  if (l16 == 0) {
#pragma unroll
    for (int vv = 0; vv < 4; ++vv) rs[t0 + 16 * w + 4 * q4 + vv] = rsum[vv];
  }
  __syncthreads();
  bf16x8 pa0 = *(const bf16x8*)&P_lds[16 * w + l16][8 * q4];
  bf16x8 pa1 = *(const bf16x8*)&P_lds[16 * w + l16][32 + 8 * q4];
  const size_t vtb = ((size_t)b * NCHUNK + c) * (size_t)D_DIM * CHUNK;
#pragma unroll 4
  for (int nt = 0; nt < 32; ++nt) {
    bf16x8 b0 = *(const bf16x8*)&VT[vtb + (size_t)(nt * 16 + l16) * CHUNK + 8 * q4];
    bf16x8 b1 = *(const bf16x8*)&VT[vtb + (size_t)(nt * 16 + l16) * CHUNK + 32 + 8 * q4];
    f32x4 acc = (f32x4){0.f, 0.f, 0.f, 0.f};
    acc = __builtin_amdgcn_mfma_f32_16x16x32_bf16(pa0, b0, acc, 0, 0, 0);
    acc = __builtin_amdgcn_mfma_f32_16x16x32_bf16(pa1, b1, acc, 0, 0, 0);
#pragma unroll
    for (int vv = 0; vv < 4; ++vv)
      numI[(t0 + 16 * w + 4 * q4 + vv) * D_DIM + nt * 16 + l16] = f2bf(acc[vv]);
  }
}

// ---------------- zscan: barrier-free z recurrence; also Pseg gate products ----------
__global__ __launch_bounds__(512) void zscan(
    const float* __restrict__ Af, const float* __restrict__ khs,
    float* __restrict__ zall, float* __restrict__ Pseg) {
  const int b = blockIdx.x;
  const int i = threadIdx.x;
  float z = 0.f, rp = 1.f;
  for (int c = 0; c < NCHUNK; ++c) {
    const size_t cb = ((size_t)b * NCHUNK + c) * D_DIM;
    zall[cb + i] = z;
    float af = Af[cb + i];
    z = fmaf(af, z, khs[cb + i]);
    rp *= af;
    if ((c & (CSEG - 1)) == CSEG - 1) {
      Pseg[((size_t)b * NSEG + (c / CSEG)) * D_DIM + i] = rp;
      rp = 1.f;
    }
  }
}

// ---------------- denk: fully parallel denominators (verified R4) ------------------
__global__ __launch_bounds__(512) void denk(
    const unsigned short* __restrict__ qt, const float* __restrict__ zall,
    float* rs_invden) {
  const int c = blockIdx.x, b = blockIdx.y;
  const int lane = threadIdx.x & 63, w = threadIdx.x >> 6;
  const size_t t0 = (size_t)b * S_DIM + (size_t)c * CHUNK;
  const size_t zb = ((size_t)b * NCHUNK + c) * D_DIM;
  float4 z0 = *(const float4*)&zall[zb + lane * 8];
  float4 z1 = *(const float4*)&zall[zb + lane * 8 + 4];
#pragma unroll
  for (int rr = 0; rr < 8; ++rr) {
    int r = 8 * w + rr;
    bf16x8 qv = *(const bf16x8*)&qt[(t0 + r) * D_DIM + lane * 8];
    float p = 0.f;
    p = fmaf(bf2f((unsigned short)qv[0]), z0.x, p);
    p = fmaf(bf2f((unsigned short)qv[1]), z0.y, p);
    p = fmaf(bf2f((unsigned short)qv[2]), z0.z, p);
    p = fmaf(bf2f((unsigned short)qv[3]), z0.w, p);
    p = fmaf(bf2f((unsigned short)qv[4]), z1.x, p);
    p = fmaf(bf2f((unsigned short)qv[5]), z1.y, p);
    p = fmaf(bf2f((unsigned short)qv[6]), z1.z, p);
    p = fmaf(bf2f((unsigned short)qv[7]), z1.w, p);
#pragma unroll
    for (int msk = 1; msk < 64; msk <<= 1) p += __shfl_xor(p, msk, 64);
    if (lane == 0) {
      float* iv = &rs_invden[t0 + r];
      *iv = 1.f / (p + *iv + EPS_C);
    }
  }
}

// ---------------- useg: per-segment state contribution, J=128 blocks ----------------
// grid (NSEG, 4 jt, B): 256 blocks = 1/CU. 8 waves = 4 i-slices x 2 j-slices;
// state slice per wave = 128 i x 64 j in registers (128 f32/lane).
// J=128 cuts the jt-redundant khT/VT re-reads 4x vs jt=16 (per-CU L1-miss bound).
__global__ __launch_bounds__(512, 2) void useg_k(
    const unsigned short* __restrict__ khT, const unsigned short* __restrict__ VT,
    const float* __restrict__ Af, unsigned short* __restrict__ U) {
  const int s = blockIdx.x, jt = blockIdx.y, b = blockIdx.z;
  const int lane = threadIdx.x & 63, w = threadIdx.x >> 6;
  const int l16 = lane & 15, q4 = lane >> 4;
  const int j0 = jt * 128;
  const int iw = 128 * (w & 3);   // i-slice base
  const int jw = 64 * (w >> 2);   // j-slice base (relative to j0)

  f32x4 acc[8][4];
#pragma unroll
  for (int T = 0; T < 8; ++T)
#pragma unroll
    for (int h = 0; h < 4; ++h) acc[T][h] = (f32x4){0.f, 0.f, 0.f, 0.f};

  for (int cc = 0; cc < CSEG; ++cc) {
    const int c = s * CSEG + cc;
    const size_t cb = ((size_t)b * NCHUNK + c) * D_DIM;
    const size_t ob = cb * CHUNK;
#pragma unroll
    for (int T = 0; T < 8; ++T) {
      float4 af = *(const float4*)&Af[cb + iw + 16 * T + 4 * q4];
#pragma unroll
      for (int h = 0; h < 4; ++h) {
        acc[T][h][0] *= af.x; acc[T][h][1] *= af.y; acc[T][h][2] *= af.z; acc[T][h][3] *= af.w;
      }
    }
    bf16x8 bv0[4], bv1[4];
#pragma unroll
    for (int h = 0; h < 4; ++h) {
      bv0[h] = *(const bf16x8*)&VT[ob + (size_t)(j0 + jw + 16 * h + l16) * CHUNK + 8 * q4];
      bv1[h] = *(const bf16x8*)&VT[ob + (size_t)(j0 + jw + 16 * h + l16) * CHUNK + 32 + 8 * q4];
    }
#pragma unroll
    for (int T = 0; T < 8; ++T) {
      bf16x8 a0 = *(const bf16x8*)&khT[ob + (size_t)(iw + 16 * T + l16) * CHUNK + 8 * q4];
      bf16x8 a1 = *(const bf16x8*)&khT[ob + (size_t)(iw + 16 * T + l16) * CHUNK + 32 + 8 * q4];
#pragma unroll
      for (int h = 0; h < 4; ++h) {
        acc[T][h] = __builtin_amdgcn_mfma_f32_16x16x32_bf16(a0, bv0[h], acc[T][h], 0, 0, 0);
        acc[T][h] = __builtin_amdgcn_mfma_f32_16x16x32_bf16(a1, bv1[h], acc[T][h], 0, 0, 0);
      }
    }
  }
  const size_t ub = ((size_t)b * NSEG + s) * D_DIM;
#pragma unroll
  for (int T = 0; T < 8; ++T)
#pragma unroll
    for (int h = 0; h < 4; ++h) {
      uint2 pk;
      pk.x = (uint32_t)f2bf(acc[T][h][0]) | ((uint32_t)f2bf(acc[T][h][1]) << 16);
      pk.y = (uint32_t)f2bf(acc[T][h][2]) | ((uint32_t)f2bf(acc[T][h][3]) << 16);
      *(uint2*)&U[(ub + j0 + jw + 16 * h + l16) * (size_t)D_DIM + iw + 16 * T + 4 * q4] = pk;
    }
}

// ---------------- sscan: in-place prefix over segments: U[s] -> Sin[s] -------------
// Sin[s] = fold_{sp<s} (acc = Pseg[sp] (*) acc + U[sp]); Sin[0] = 0.
// One thread owns (b, j, 8 consecutive i) for all s -> in-place safe, coalesced.
__global__ __launch_bounds__(256) void sscan(
    const float* __restrict__ Pseg, unsigned short* __restrict__ U) {
  const int b = blockIdx.y;
  const int flat = blockIdx.x * 256 + threadIdx.x;   // 0 .. 32767
  const int j = flat >> 6;
  const int i0 = (flat & 63) * 8;
  float acc[8];
#pragma unroll
  for (int t = 0; t < 8; ++t) acc[t] = 0.f;
  for (int s = 0; s < NSEG; ++s) {
    const size_t pb = ((size_t)b * NSEG + s) * D_DIM;
    unsigned short* up = &U[(pb + j) * (size_t)D_DIM + i0];
    uint4 u = *(const uint4*)up;
    float4 p0 = *(const float4*)&Pseg[pb + i0];
    float4 p1 = *(const float4*)&Pseg[pb + i0 + 4];
    float uv[8];
    uv[0] = bf2f((unsigned short)(u.x & 0xffff)); uv[1] = bf2f((unsigned short)(u.x >> 16));
    uv[2] = bf2f((unsigned short)(u.y & 0xffff)); uv[3] = bf2f((unsigned short)(u.y >> 16));
    uv[4] = bf2f((unsigned short)(u.z & 0xffff)); uv[5] = bf2f((unsigned short)(u.z >> 16));
    uv[6] = bf2f((unsigned short)(u.w & 0xffff)); uv[7] = bf2f((unsigned short)(u.w >> 16));
    uint4 o;
    o.x = (uint32_t)f2bf(acc[0]) | ((uint32_t)f2bf(acc[1]) << 16);
    o.y = (uint32_t)f2bf(acc[2]) | ((uint32_t)f2bf(acc[3]) << 16);
    o.z = (uint32_t)f2bf(acc[4]) | ((uint32_t)f2bf(acc[5]) << 16);
    o.w = (uint32_t)f2bf(acc[6]) | ((uint32_t)f2bf(acc[7]) << 16);
    *(uint4*)up = o;
    acc[0] = fmaf(p0.x, acc[0], uv[0]);
    acc[1] = fmaf(p0.y, acc[1], uv[1]);
    acc[2] = fmaf(p0.z, acc[2], uv[2]);
    acc[3] = fmaf(p0.w, acc[3], uv[3]);
    acc[4] = fmaf(p1.x, acc[4], uv[4]);
    acc[5] = fmaf(p1.y, acc[5], uv[5]);
    acc[6] = fmaf(p1.z, acc[6], uv[6]);
    acc[7] = fmaf(p1.w, acc[7], uv[7]);
  }
}

// ---------------- scan2: segment replay, J=128 blocks ------------------------------
// grid (NSEG, 4 jt, B): 256 blocks = 1/CU. All 8 waves do BOTH roles per chunk:
// (a) O-compute from S^T staged in LDS, (b) state update in registers.
// J=128 cuts jt-redundant qt/khT re-reads 4x (scan2 was per-CU L1-miss bound:
// 1.1 GB reads at ~7 B/cyc/CU = the whole 250 us; now ~0.33 GB).
__global__ __launch_bounds__(512, 2) void scan2(
    const unsigned short* __restrict__ qt, const unsigned short* __restrict__ khT,
    const unsigned short* __restrict__ VT, const float* __restrict__ Af,
    const unsigned short* __restrict__ Sin,
    const unsigned short* __restrict__ numI, const float* __restrict__ invden,
    float* __restrict__ out) {
  __shared__ unsigned short STj[128][520];  // S^T: [j_local][i] bf16, 133 KB
  const int s = blockIdx.x, jt = blockIdx.y, b = blockIdx.z;
  const int lane = threadIdx.x & 63, w = threadIdx.x >> 6;   // wave-uniform w
  const int l16 = lane & 15, q4 = lane >> 4;
  const int j0 = jt * 128;
  const int iw = 128 * (w & 3);   // state i-slice
  const int jw = 64 * (w >> 2);   // state j-slice (relative to j0)
  const int rw = 16 * (w & 3);    // O row-tile
  const int jo = 64 * (w >> 2);   // O j-half (relative to j0)

  f32x4 acc[8][4];

  // initial state for this segment, precomputed by sscan (uniform, single load)
  {
    const size_t pb = ((size_t)b * NSEG + s) * D_DIM;
#pragma unroll
    for (int T = 0; T < 8; ++T)
#pragma unroll
      for (int h = 0; h < 4; ++h) {
        uint2 uu = *(const uint2*)&Sin[(pb + j0 + jw + 16 * h + l16) * (size_t)D_DIM + iw + 16 * T + 4 * q4];
        acc[T][h][0] = bf2f((unsigned short)(uu.x & 0xffff));
        acc[T][h][1] = bf2f((unsigned short)(uu.x >> 16));
        acc[T][h][2] = bf2f((unsigned short)(uu.y & 0xffff));
        acc[T][h][3] = bf2f((unsigned short)(uu.y >> 16));
      }
  }

  for (int cc = 0; cc < CSEG; ++cc) {
    const int c = s * CSEG + cc;
    const size_t cb = ((size_t)b * NCHUNK + c) * D_DIM;
    const size_t t0 = (size_t)b * S_DIM + (size_t)c * CHUNK;
    const size_t ob = cb * CHUNK;

    // stage pre-update state S^T into LDS (each wave its slice)
#pragma unroll
    for (int T = 0; T < 8; ++T)
#pragma unroll
      for (int h = 0; h < 4; ++h) {
        uint2 pk;
        pk.x = (uint32_t)f2bf(acc[T][h][0]) | ((uint32_t)f2bf(acc[T][h][1]) << 16);
        pk.y = (uint32_t)f2bf(acc[T][h][2]) | ((uint32_t)f2bf(acc[T][h][3]) << 16);
        *(uint2*)&STj[jw + 16 * h + l16][iw + 16 * T + 4 * q4] = pk;
      }
    __syncthreads();

    // (a) O-compute: out rows [rw,rw+16) x cols [j0+jo, j0+jo+64)
    {
      f32x4 accO[4];
#pragma unroll
      for (int h = 0; h < 4; ++h) accO[h] = (f32x4){0.f, 0.f, 0.f, 0.f};
#pragma unroll
      for (int ks = 0; ks < 16; ++ks) {
        bf16x8 afr = *(const bf16x8*)&qt[(t0 + rw + l16) * D_DIM + 32 * ks + 8 * q4];
#pragma unroll
        for (int h = 0; h < 4; ++h) {
          bf16x8 bfr = *(const bf16x8*)&STj[jo + 16 * h + l16][32 * ks + 8 * q4];
          accO[h] = __builtin_amdgcn_mfma_f32_16x16x32_bf16(afr, bfr, accO[h], 0, 0, 0);
        }
      }
#pragma unroll
      for (int h = 0; h < 4; ++h)
#pragma unroll
        for (int vv = 0; vv < 4; ++vv) {
          size_t t = t0 + rw + 4 * q4 + vv;
          int j = j0 + jo + 16 * h + l16;
          float idv = invden[t];
          float nI = bf2f(numI[t * D_DIM + j]);
          out[t * D_DIM + j] = (accO[h][vv] + nI) * idv;
        }
    }

    // (b) state update (skip on last chunk: result unused)
    if (cc != CSEG - 1) {
#pragma unroll
      for (int T = 0; T < 8; ++T) {
        float4 af = *(const float4*)&Af[cb + iw + 16 * T + 4 * q4];
#pragma unroll
        for (int h = 0; h < 4; ++h) {
          acc[T][h][0] *= af.x; acc[T][h][1] *= af.y; acc[T][h][2] *= af.z; acc[T][h][3] *= af.w;
        }
      }
      bf16x8 bv0[4], bv1[4];
#pragma unroll
      for (int h = 0; h < 4; ++h) {
        bv0[h] = *(const bf16x8*)&VT[ob + (size_t)(j0 + jw + 16 * h + l16) * CHUNK + 8 * q4];
        bv1[h] = *(const bf16x8*)&VT[ob + (size_t)(j0 + jw + 16 * h + l16) * CHUNK + 32 + 8 * q4];
      }
#pragma unroll
      for (int T = 0; T < 8; ++T) {
        bf16x8 a0 = *(const bf16x8*)&khT[ob + (size_t)(iw + 16 * T + l16) * CHUNK + 8 * q4];
        bf16x8 a1 = *(const bf16x8*)&khT[ob + (size_t)(iw + 16 * T + l16) * CHUNK + 32 + 8 * q4];
#pragma unroll
        for (int h = 0; h < 4; ++h) {
          acc[T][h] = __builtin_amdgcn_mfma_f32_16x16x32_bf16(a0, bv0[h], acc[T][h], 0, 0, 0);
          acc[T][h] = __builtin_amdgcn_mfma_f32_16x16x32_bf16(a1, bv1[h], acc[T][h], 0, 0, 0);
        }
      }
    }
    __syncthreads();
  }
}

// ---------------- launch ----------------
extern "C" void kernel_launch(void* const* d_in, const int* in_sizes, int n_in,
                              void* d_out, int out_size, void* d_ws, size_t ws_size,
                              hipStream_t stream) {
  const float* x  = (const float*)d_in[0];
  const float* Wq = (const float*)d_in[1];
  const float* bq = (const float*)d_in[2];
  const float* Wk = (const float*)d_in[3];
  const float* bk = (const float*)d_in[4];
  const float* Wv = (const float*)d_in[5];
  const float* bv = (const float*)d_in[6];
  const float* Wa = (const float*)d_in[7];
  const float* ba = (const float*)d_in[8];
  float* out = (float*)d_out;

  // Workspace layout identical to R3/R4 (proven): ~172 MB.
  const size_t MD2 = (size_t)M_DIM * D_DIM * 2;
  uint8_t* w = (uint8_t*)d_ws;
  unsigned short* xb   = (unsigned short*)w; w += MD2;
  unsigned short* wb   = (unsigned short*)w; w += (size_t)4 * D_DIM * D_DIM * 2;  // 2 MB
  unsigned short* q_ws = (unsigned short*)w; w += MD2;
  unsigned short* k_ws = (unsigned short*)w; w += MD2;
  unsigned short* v_ws = (unsigned short*)w; w += MD2;
  unsigned short* g_ws = (unsigned short*)w; w += MD2;
  float* Af     = (float*)w; w += (size_t)B_DIM * NCHUNK * D_DIM * 4;  // 1 MB
  float* khs    = (float*)w; w += (size_t)B_DIM * NCHUNK * D_DIM * 4;  // 1 MB
  float* invden = (float*)w; w += (size_t)M_DIM * 4;                   // 128 KB

  unsigned short* qt   = xb;     // xb dead after proj_gemm
  unsigned short* kt   = q_ws;   // same-index overwrite inside prep
  unsigned short* kh   = k_ws;   // same-index overwrite inside prep
  unsigned short* VT   = g_ws;   // g dead after prep
  unsigned short* khT  = v_ws;   // v dead after its transpose
  unsigned short* numI = q_ws;   // kt dead after intra's P-phase
  unsigned short* U    = k_ws;   // kh dead after khT transpose; NSEG*B*512*512*2 == MD2 exactly
  float* zall = (float*)wb;                          // wb dead after proj; 1 MB
  float* Pseg = (float*)((uint8_t*)wb + (1 << 20));  // 128 KB

  cvt_f32_bf16<<<1024, 256, 0, stream>>>(x, xb, M_DIM * D_DIM / 4);
  cvt_f32_bf16<<<128, 256, 0, stream>>>(Wq, wb + 0 * D_DIM * D_DIM, D_DIM * D_DIM / 4);
  cvt_f32_bf16<<<128, 256, 0, stream>>>(Wk, wb + 1 * D_DIM * D_DIM, D_DIM * D_DIM / 4);
  cvt_f32_bf16<<<128, 256, 0, stream>>>(Wv, wb + 2 * D_DIM * D_DIM, D_DIM * D_DIM / 4);
  cvt_f32_bf16<<<128, 256, 0, stream>>>(Wa, wb + 3 * D_DIM * D_DIM, D_DIM * D_DIM / 4);

  proj_gemm<<<dim3(M_DIM / TM, D_DIM / TN, 4), 256, 0, stream>>>(
      xb, wb, bq, bk, bv, ba, q_ws, k_ws, v_ws, g_ws);

  prep<<<dim3(NCHUNK, B_DIM), 512, 0, stream>>>(q_ws, k_ws, g_ws, qt, kt, kh, Af, khs);
  transpose_cd<<<dim3(NCHUNK, B_DIM), 256, 0, stream>>>(v_ws, VT);
  transpose_cd<<<dim3(NCHUNK, B_DIM), 256, 0, stream>>>(kh, khT);
  zscan<<<B_DIM, 512, 0, stream>>>(Af, khs, zall, Pseg);
  intra<<<dim3(NCHUNK, B_DIM), 256, 0, stream>>>(qt, kt, VT, numI, invden);
  denk<<<dim3(NCHUNK, B_DIM), 512, 0, stream>>>(qt, zall, invden);
  useg_k<<<dim3(NSEG, 4, B_DIM), 512, 0, stream>>>(khT, VT, Af, U);
  sscan<<<dim3(128, B_DIM), 256, 0, stream>>>(Pseg, U);   // U -> Sin in place
  scan2<<<dim3(NSEG, 4, B_DIM), 512, 0, stream>>>(qt, khT, VT, Af, U, numI, invden, out);
}

// Round 4
// 530.681 us; speedup vs baseline: 1.4289x; 1.0716x over previous
//
#include <hip/hip_runtime.h>
#include <hip/hip_bf16.h>
#include <cstdint>
#include <cstddef>

#define D_DIM 512
#define B_DIM 8
#define S_DIM 4096
#define M_DIM (B_DIM * S_DIM)   // 32768 tokens
#define CHUNK 64
#define NCHUNK (S_DIM / CHUNK)  // 64 chunks per batch
#define NSEG 8
#define CSEG (NCHUNK / NSEG)    // 8 chunks per segment
#define EPS_C 1e-6f

typedef __attribute__((ext_vector_type(8))) short bf16x8;
typedef __attribute__((ext_vector_type(4))) float f32x4;

__device__ __forceinline__ unsigned short f2bf(float f) {
  uint32_t u = __float_as_uint(f);
  u = (u + 0x7fffu + ((u >> 16) & 1u)) >> 16;   // RNE; inputs finite
  return (unsigned short)u;
}
__device__ __forceinline__ float bf2f(unsigned short s) { return __uint_as_float(((uint32_t)s) << 16); }

// ---------------- fp32 -> bf16 conversion ----------------
__global__ void cvt_f32_bf16(const float* __restrict__ in, unsigned short* __restrict__ out, int n4) {
  int i = blockIdx.x * blockDim.x + threadIdx.x;
  int stride = gridDim.x * blockDim.x;
  for (; i < n4; i += stride) {
    float4 f = ((const float4*)in)[i];
    ushort4 o;
    o.x = f2bf(f.x); o.y = f2bf(f.y); o.z = f2bf(f.z); o.w = f2bf(f.w);
    ((ushort4*)out)[i] = o;
  }
}

// ---------------- fused projection GEMM, async global->LDS staging (m97 pattern) ----
// Epilogue: per-wave-private LDS transpose (reuses staging buffer) -> bf16x8 coalesced
// stores, full 64B sectors (was: scalar ushort stores, 2.14x write amplification).
#define TM 128
#define TN 128
#define BK 32

__global__ __launch_bounds__(256) void proj_gemm(
    const unsigned short* __restrict__ Xb,
    const unsigned short* __restrict__ Wb,
    const float* __restrict__ bq, const float* __restrict__ bk,
    const float* __restrict__ bv, const float* __restrict__ ba,
    unsigned short* __restrict__ q_ws, unsigned short* __restrict__ k_ws,
    unsigned short* __restrict__ v_ws, unsigned short* __restrict__ g_ws) {
  __shared__ unsigned short SB[TM * BK + TN * BK];   // 16 KB (staging; reused by epilogue)
  unsigned short* As = SB;
  unsigned short* Bs = SB + TM * BK;

  const int proj = blockIdx.z;
  const unsigned short* W = Wb + (size_t)proj * D_DIM * D_DIM;
  const int m0 = blockIdx.x * TM;
  const int n0 = blockIdx.y * TN;
  const int tid = threadIdx.x;
  const int lane = tid & 63;
  const int wave = tid >> 6;
  const int wm = (wave & 1) * 64;
  const int wn = (wave >> 1) * 64;
  const int quad = lane >> 4;
  const int l16 = lane & 15;

  f32x4 acc[4][4];
#pragma unroll
  for (int i = 0; i < 4; ++i)
#pragma unroll
    for (int j = 0; j < 4; ++j) acc[i][j] = (f32x4){0.f, 0.f, 0.f, 0.f};

  const int rw = lane >> 2;           // row within 16-row wave slab
  const int kq = (lane & 3) * 8;      // k offset (8 shorts = 16B)

  for (int kc = 0; kc < D_DIM; kc += BK) {
    __syncthreads();  // previous chunk's fragment reads done
    {
      const unsigned short* gA0 = &Xb[(size_t)(m0 + wave * 16 + rw) * D_DIM + kc + kq];
      const unsigned short* gA1 = &Xb[(size_t)(m0 + 64 + wave * 16 + rw) * D_DIM + kc + kq];
      const unsigned short* gB0 = &W[(size_t)(n0 + wave * 16 + rw) * D_DIM + kc + kq];
      const unsigned short* gB1 = &W[(size_t)(n0 + 64 + wave * 16 + rw) * D_DIM + kc + kq];
      __builtin_amdgcn_global_load_lds(
          (const __attribute__((address_space(1))) void*)gA0,
          (__attribute__((address_space(3))) void*)&As[(wave * 16) * BK], 16, 0, 0);
      __builtin_amdgcn_global_load_lds(
          (const __attribute__((address_space(1))) void*)gA1,
          (__attribute__((address_space(3))) void*)&As[(64 + wave * 16) * BK], 16, 0, 0);
      __builtin_amdgcn_global_load_lds(
          (const __attribute__((address_space(1))) void*)gB0,
          (__attribute__((address_space(3))) void*)&Bs[(wave * 16) * BK], 16, 0, 0);
      __builtin_amdgcn_global_load_lds(
          (const __attribute__((address_space(1))) void*)gB1,
          (__attribute__((address_space(3))) void*)&Bs[(64 + wave * 16) * BK], 16, 0, 0);
    }
    __syncthreads();  // barrier drains vmcnt -> staged data visible

    bf16x8 afr[4], bfr[4];
#pragma unroll
    for (int im = 0; im < 4; ++im)
      afr[im] = *(const bf16x8*)&As[(wm + im * 16 + l16) * BK + quad * 8];
#pragma unroll
    for (int in = 0; in < 4; ++in)
      bfr[in] = *(const bf16x8*)&Bs[(wn + in * 16 + l16) * BK + quad * 8];
#pragma unroll
    for (int im = 0; im < 4; ++im)
#pragma unroll
      for (int in = 0; in < 4; ++in)
        acc[im][in] = __builtin_amdgcn_mfma_f32_16x16x32_bf16(afr[im], bfr[in], acc[im][in], 0, 0, 0);
  }

  __syncthreads();   // all fragment reads done before LDS reuse by epilogue

  const float* bias = (proj == 0) ? bq : (proj == 1) ? bk : (proj == 2) ? bv : ba;
  unsigned short* outp = (proj == 0) ? q_ws : (proj == 1) ? k_ws : (proj == 2) ? v_ws : g_ws;
  const bool do_relu = (proj <= 1);
  unsigned short* EP = &SB[wave * 64 * 32];   // per-wave-private 64x32 bf16 (4 KB)

#pragma unroll
  for (int p = 0; p < 2; ++p) {   // column halves of the wave's 64x64 tile
#pragma unroll
    for (int half = 0; half < 2; ++half) {
      const int in = 2 * p + half;
      const int nn = n0 + wn + in * 16 + l16;
      const float bn = bias[nn];
#pragma unroll
      for (int im = 0; im < 4; ++im) {
#pragma unroll
        for (int vv = 0; vv < 4; ++vv) {
          float val = acc[im][in][vv] + bn;
          if (do_relu) val = fmaxf(val, 0.f);
          EP[(im * 16 + quad * 4 + vv) * 32 + half * 16 + l16] = f2bf(val);
        }
      }
    }
    // coalesced store: lane -> (row = it*16 + lane>>2, 8 cols at (lane&3)*8)
#pragma unroll
    for (int it = 0; it < 4; ++it) {
      const int row = it * 16 + (lane >> 2);
      const int ccol = (lane & 3) * 8;
      bf16x8 vdat = *(const bf16x8*)&EP[row * 32 + ccol];
      size_t gidx = (size_t)(m0 + wm + row) * D_DIM + (size_t)(n0 + wn + p * 32 + ccol);
      *(bf16x8*)&outp[gidx] = vdat;
    }
  }
}

// ---------------- prep: cum-factorized operands, segmented + bf16x8-vectorized -----
// 8 row-segments x 64 col-group threads. Pass A: per-segment sigmoid products
// (bf16x8 loads); LDS prefix over segments; Pass B: local cumprod seeded by prefix,
// all loads/stores 16B. Same math as R3-verified scalar version up to fp32
// association order (noise ~1e-7 rel, << bf16 quantization of all operands).
__global__ __launch_bounds__(512) void prep(
    const unsigned short* __restrict__ q, const unsigned short* __restrict__ k,
    const unsigned short* __restrict__ g,
    unsigned short* __restrict__ qt, unsigned short* __restrict__ kt,
    unsigned short* __restrict__ kh,
    float* __restrict__ Af, float* __restrict__ khs) {
  __shared__ float segp[8][512];   // 16 KB
  const int c = blockIdx.x, b = blockIdx.y;
  const int seg = threadIdx.x >> 6;   // 8 segments x 8 rows
  const int t = threadIdx.x & 63;
  const int i0 = t * 8;               // 8 cols per thread
  const int r0 = seg * 8;
  const size_t t0 = (size_t)b * S_DIM + (size_t)c * CHUNK;
  const size_t cb = ((size_t)b * NCHUNK + c) * D_DIM;

  // Pass A: segment product of sigmoids
  float sp[8];
#pragma unroll
  for (int j = 0; j < 8; ++j) sp[j] = 1.f;
  for (int r = 0; r < 8; ++r) {
    bf16x8 gv = *(const bf16x8*)&g[(t0 + r0 + r) * D_DIM + i0];
#pragma unroll
    for (int j = 0; j < 8; ++j)
      sp[j] *= 1.f / (1.f + __expf(-bf2f((unsigned short)gv[j])));
  }
  *(float4*)&segp[seg][i0] = *(float4*)&sp[0];
  *(float4*)&segp[seg][i0 + 4] = *(float4*)&sp[4];
  __syncthreads();

  // prefix (segments < seg) and total products
  float pre[8], tot[8];
#pragma unroll
  for (int j = 0; j < 8; ++j) { pre[j] = 1.f; tot[j] = 1.f; }
  for (int s2 = 0; s2 < 8; ++s2) {
    float4 v0 = *(const float4*)&segp[s2][i0];
    float4 v1 = *(const float4*)&segp[s2][i0 + 4];
    float v[8] = {v0.x, v0.y, v0.z, v0.w, v1.x, v1.y, v1.z, v1.w};
#pragma unroll
    for (int j = 0; j < 8; ++j) {
      tot[j] *= v[j];
      if (s2 < seg) pre[j] *= v[j];
    }
  }
  if (seg == 0) {
    float4 a0 = {tot[0], tot[1], tot[2], tot[3]};
    float4 a1 = {tot[4], tot[5], tot[6], tot[7]};
    *(float4*)&Af[cb + i0] = a0;
    *(float4*)&Af[cb + i0 + 4] = a1;
  }

  // Pass B: cumprod from prefix; emit qt/kt/kh; accumulate khs partial
  float cum[8], ssum[8];
#pragma unroll
  for (int j = 0; j < 8; ++j) { cum[j] = pre[j]; ssum[j] = 0.f; }
  for (int r = 0; r < 8; ++r) {
    size_t idx = (t0 + r0 + r) * D_DIM + i0;
    bf16x8 gv = *(const bf16x8*)&g[idx];
    bf16x8 qv8 = *(const bf16x8*)&q[idx];
    bf16x8 kv8 = *(const bf16x8*)&k[idx];
    bf16x8 oq, ok, okh;
#pragma unroll
    for (int j = 0; j < 8; ++j) {
      cum[j] *= 1.f / (1.f + __expf(-bf2f((unsigned short)gv[j])));
      float qv = bf2f((unsigned short)qv8[j]);
      float kv = bf2f((unsigned short)kv8[j]);
      oq[j] = (short)f2bf(qv * cum[j]);
      float inv = 1.f / cum[j];
      ok[j] = (short)f2bf(kv * inv);
      float khf = kv * (tot[j] * inv);
      okh[j] = (short)f2bf(khf);
      ssum[j] += khf;
    }
    *(bf16x8*)&qt[idx] = oq;
    *(bf16x8*)&kt[idx] = ok;
    *(bf16x8*)&kh[idx] = okh;
  }

  // khs: cross-segment reduction via LDS
  __syncthreads();
  *(float4*)&segp[seg][i0] = *(float4*)&ssum[0];
  *(float4*)&segp[seg][i0 + 4] = *(float4*)&ssum[4];
  __syncthreads();
  if (seg == 0) {
    float s[8];
#pragma unroll
    for (int j = 0; j < 8; ++j) s[j] = 0.f;
    for (int s2 = 0; s2 < 8; ++s2) {
      float4 v0 = *(const float4*)&segp[s2][i0];
      float4 v1 = *(const float4*)&segp[s2][i0 + 4];
      s[0] += v0.x; s[1] += v0.y; s[2] += v0.z; s[3] += v0.w;
      s[4] += v1.x; s[5] += v1.y; s[6] += v1.z; s[7] += v1.w;
    }
    float4 a0 = {s[0], s[1], s[2], s[3]};
    float4 a1 = {s[4], s[5], s[6], s[7]};
    *(float4*)&khs[cb + i0] = a0;
    *(float4*)&khs[cb + i0 + 4] = a1;
  }
}

// ---------------- per-chunk transpose [r][i] -> [i][r] (verified R3) ----------------
__global__ __launch_bounds__(256) void transpose_cd(
    const unsigned short* __restrict__ in, unsigned short* __restrict__ outT) {
  __shared__ unsigned short tile[CHUNK][264];
  const int c = blockIdx.x, b = blockIdx.y;
  const size_t base_in = ((size_t)b * S_DIM + (size_t)c * CHUNK) * D_DIM;
  const size_t base_out = ((size_t)b * NCHUNK + c) * (size_t)D_DIM * CHUNK;
  const int tid = threadIdx.x;
#pragma unroll
  for (int h = 0; h < 2; ++h) {
    if (h) __syncthreads();
#pragma unroll
    for (int it = 0; it < 8; ++it) {
      int flat = (it * 256 + tid) * 8;
      int row = flat >> 8;
      int col = flat & 255;
      *(uint4*)&tile[row][col] = *(const uint4*)&in[base_in + (size_t)row * D_DIM + h * 256 + col];
    }
    __syncthreads();
#pragma unroll
    for (int it = 0; it < 8; ++it) {
      int wq = it * 256 + tid;
      int i_loc = wq >> 3;
      int r0 = (wq & 7) * 8;
      ushort4 v0, v1;
      v0.x = tile[r0 + 0][i_loc]; v0.y = tile[r0 + 1][i_loc];
      v0.z = tile[r0 + 2][i_loc]; v0.w = tile[r0 + 3][i_loc];
      v1.x = tile[r0 + 4][i_loc]; v1.y = tile[r0 + 5][i_loc];
      v1.z = tile[r0 + 6][i_loc]; v1.w = tile[r0 + 7][i_loc];
      size_t o = base_out + (size_t)(h * 256 + i_loc) * CHUNK + r0;
      *(ushort4*)&outT[o] = v0;
      *(ushort4*)&outT[o + 4] = v1;
    }
  }
}

// ---------------- intra-chunk: P = mask(qt·kt^T), rowsums, numI = P·V (verified R3) ----
__global__ __launch_bounds__(256) void intra(
    const unsigned short* __restrict__ qt, const unsigned short* kt,
    const unsigned short* __restrict__ VT,
    unsigned short* numI, float* __restrict__ rs) {
  __shared__ unsigned short P_lds[CHUNK][CHUNK + 8];
  const int c = blockIdx.x, b = blockIdx.y;
  const size_t t0 = (size_t)b * S_DIM + (size_t)c * CHUNK;
  const int lane = threadIdx.x & 63, w = threadIdx.x >> 6;
  const int l16 = lane & 15, q4 = lane >> 4;

  f32x4 accP[4];
#pragma unroll
  for (int n = 0; n < 4; ++n) accP[n] = (f32x4){0.f, 0.f, 0.f, 0.f};
#pragma unroll
  for (int ks = 0; ks < 16; ++ks) {
    bf16x8 afr = *(const bf16x8*)&qt[(t0 + 16 * w + l16) * D_DIM + 32 * ks + 8 * q4];
#pragma unroll
    for (int n = 0; n < 4; ++n) {
      bf16x8 bfr = *(const bf16x8*)&kt[(t0 + 16 * n + l16) * D_DIM + 32 * ks + 8 * q4];
      accP[n] = __builtin_amdgcn_mfma_f32_16x16x32_bf16(afr, bfr, accP[n], 0, 0, 0);
    }
  }
  float rsum[4] = {0.f, 0.f, 0.f, 0.f};
#pragma unroll
  for (int n = 0; n < 4; ++n) {
    int m = 16 * n + l16;
#pragma unroll
    for (int vv = 0; vv < 4; ++vv) {
      int r = 16 * w + 4 * q4 + vv;
      float pv = (m <= r) ? accP[n][vv] : 0.f;
      rsum[vv] += pv;
      P_lds[r][m] = f2bf(pv);
    }
  }
#pragma unroll
  for (int msk = 1; msk < 16; msk <<= 1) {
#pragma unroll
    for (int vv = 0; vv < 4; ++vv) rsum[vv] += __shfl_xor(rsum[vv], msk, 64);
  }
  if (l16 == 0) {
#pragma unroll
    for (int vv = 0; vv < 4; ++vv) rs[t0 + 16 * w + 4 * q4 + vv] = rsum[vv];
  }
  __syncthreads();
  bf16x8 pa0 = *(const bf16x8*)&P_lds[16 * w + l16][8 * q4];
  bf16x8 pa1 = *(const bf16x8*)&P_lds[16 * w + l16][32 + 8 * q4];
  const size_t vtb = ((size_t)b * NCHUNK + c) * (size_t)D_DIM * CHUNK;
#pragma unroll 4
  for (int nt = 0; nt < 32; ++nt) {
    bf16x8 b0 = *(const bf16x8*)&VT[vtb + (size_t)(nt * 16 + l16) * CHUNK + 8 * q4];
    bf16x8 b1 = *(const bf16x8*)&VT[vtb + (size_t)(nt * 16 + l16) * CHUNK + 32 + 8 * q4];
    f32x4 acc = (f32x4){0.f, 0.f, 0.f, 0.f};
    acc = __builtin_amdgcn_mfma_f32_16x16x32_bf16(pa0, b0, acc, 0, 0, 0);
    acc = __builtin_amdgcn_mfma_f32_16x16x32_bf16(pa1, b1, acc, 0, 0, 0);
#pragma unroll
    for (int vv = 0; vv < 4; ++vv)
      numI[(t0 + 16 * w + 4 * q4 + vv) * D_DIM + nt * 16 + l16] = f2bf(acc[vv]);
  }
}

// ---------------- zscan: barrier-free z recurrence; also Pseg gate products ----------
__global__ __launch_bounds__(512) void zscan(
    const float* __restrict__ Af, const float* __restrict__ khs,
    float* __restrict__ zall, float* __restrict__ Pseg) {
  const int b = blockIdx.x;
  const int i = threadIdx.x;
  float z = 0.f, rp = 1.f;
  for (int c = 0; c < NCHUNK; ++c) {
    const size_t cb = ((size_t)b * NCHUNK + c) * D_DIM;
    zall[cb + i] = z;
    float af = Af[cb + i];
    z = fmaf(af, z, khs[cb + i]);
    rp *= af;
    if ((c & (CSEG - 1)) == CSEG - 1) {
      Pseg[((size_t)b * NSEG + (c / CSEG)) * D_DIM + i] = rp;
      rp = 1.f;
    }
  }
}

// ---------------- denk: fully parallel denominators (verified R4) ------------------
__global__ __launch_bounds__(512) void denk(
    const unsigned short* __restrict__ qt, const float* __restrict__ zall,
    float* rs_invden) {
  const int c = blockIdx.x, b = blockIdx.y;
  const int lane = threadIdx.x & 63, w = threadIdx.x >> 6;
  const size_t t0 = (size_t)b * S_DIM + (size_t)c * CHUNK;
  const size_t zb = ((size_t)b * NCHUNK + c) * D_DIM;
  float4 z0 = *(const float4*)&zall[zb + lane * 8];
  float4 z1 = *(const float4*)&zall[zb + lane * 8 + 4];
#pragma unroll
  for (int rr = 0; rr < 8; ++rr) {
    int r = 8 * w + rr;
    bf16x8 qv = *(const bf16x8*)&qt[(t0 + r) * D_DIM + lane * 8];
    float p = 0.f;
    p = fmaf(bf2f((unsigned short)qv[0]), z0.x, p);
    p = fmaf(bf2f((unsigned short)qv[1]), z0.y, p);
    p = fmaf(bf2f((unsigned short)qv[2]), z0.z, p);
    p = fmaf(bf2f((unsigned short)qv[3]), z0.w, p);
    p = fmaf(bf2f((unsigned short)qv[4]), z1.x, p);
    p = fmaf(bf2f((unsigned short)qv[5]), z1.y, p);
    p = fmaf(bf2f((unsigned short)qv[6]), z1.z, p);
    p = fmaf(bf2f((unsigned short)qv[7]), z1.w, p);
#pragma unroll
    for (int msk = 1; msk < 64; msk <<= 1) p += __shfl_xor(p, msk, 64);
    if (lane == 0) {
      float* iv = &rs_invden[t0 + r];
      *iv = 1.f / (p + *iv + EPS_C);
    }
  }
}

// ---------------- useg: per-segment state contribution, J=128 blocks ----------------
__global__ __launch_bounds__(512, 2) void useg_k(
    const unsigned short* __restrict__ khT, const unsigned short* __restrict__ VT,
    const float* __restrict__ Af, unsigned short* __restrict__ U) {
  const int s = blockIdx.x, jt = blockIdx.y, b = blockIdx.z;
  const int lane = threadIdx.x & 63, w = threadIdx.x >> 6;
  const int l16 = lane & 15, q4 = lane >> 4;
  const int j0 = jt * 128;
  const int iw = 128 * (w & 3);   // i-slice base
  const int jw = 64 * (w >> 2);   // j-slice base (relative to j0)

  f32x4 acc[8][4];
#pragma unroll
  for (int T = 0; T < 8; ++T)
#pragma unroll
    for (int h = 0; h < 4; ++h) acc[T][h] = (f32x4){0.f, 0.f, 0.f, 0.f};

  for (int cc = 0; cc < CSEG; ++cc) {
    const int c = s * CSEG + cc;
    const size_t cb = ((size_t)b * NCHUNK + c) * D_DIM;
    const size_t ob = cb * CHUNK;
#pragma unroll
    for (int T = 0; T < 8; ++T) {
      float4 af = *(const float4*)&Af[cb + iw + 16 * T + 4 * q4];
#pragma unroll
      for (int h = 0; h < 4; ++h) {
        acc[T][h][0] *= af.x; acc[T][h][1] *= af.y; acc[T][h][2] *= af.z; acc[T][h][3] *= af.w;
      }
    }
    bf16x8 bv0[4], bv1[4];
#pragma unroll
    for (int h = 0; h < 4; ++h) {
      bv0[h] = *(const bf16x8*)&VT[ob + (size_t)(j0 + jw + 16 * h + l16) * CHUNK + 8 * q4];
      bv1[h] = *(const bf16x8*)&VT[ob + (size_t)(j0 + jw + 16 * h + l16) * CHUNK + 32 + 8 * q4];
    }
#pragma unroll
    for (int T = 0; T < 8; ++T) {
      bf16x8 a0 = *(const bf16x8*)&khT[ob + (size_t)(iw + 16 * T + l16) * CHUNK + 8 * q4];
      bf16x8 a1 = *(const bf16x8*)&khT[ob + (size_t)(iw + 16 * T + l16) * CHUNK + 32 + 8 * q4];
#pragma unroll
      for (int h = 0; h < 4; ++h) {
        acc[T][h] = __builtin_amdgcn_mfma_f32_16x16x32_bf16(a0, bv0[h], acc[T][h], 0, 0, 0);
        acc[T][h] = __builtin_amdgcn_mfma_f32_16x16x32_bf16(a1, bv1[h], acc[T][h], 0, 0, 0);
      }
    }
  }
  const size_t ub = ((size_t)b * NSEG + s) * D_DIM;
#pragma unroll
  for (int T = 0; T < 8; ++T)
#pragma unroll
    for (int h = 0; h < 4; ++h) {
      uint2 pk;
      pk.x = (uint32_t)f2bf(acc[T][h][0]) | ((uint32_t)f2bf(acc[T][h][1]) << 16);
      pk.y = (uint32_t)f2bf(acc[T][h][2]) | ((uint32_t)f2bf(acc[T][h][3]) << 16);
      *(uint2*)&U[(ub + j0 + jw + 16 * h + l16) * (size_t)D_DIM + iw + 16 * T + 4 * q4] = pk;
    }
}

// ---------------- sscan: in-place prefix over segments: U[s] -> Sin[s] -------------
__global__ __launch_bounds__(256) void sscan(
    const float* __restrict__ Pseg, unsigned short* __restrict__ U) {
  const int b = blockIdx.y;
  const int flat = blockIdx.x * 256 + threadIdx.x;   // 0 .. 32767
  const int j = flat >> 6;
  const int i0 = (flat & 63) * 8;
  float acc[8];
#pragma unroll
  for (int t = 0; t < 8; ++t) acc[t] = 0.f;
  for (int s = 0; s < NSEG; ++s) {
    const size_t pb = ((size_t)b * NSEG + s) * D_DIM;
    unsigned short* up = &U[(pb + j) * (size_t)D_DIM + i0];
    uint4 u = *(const uint4*)up;
    float4 p0 = *(const float4*)&Pseg[pb + i0];
    float4 p1 = *(const float4*)&Pseg[pb + i0 + 4];
    float uv[8];
    uv[0] = bf2f((unsigned short)(u.x & 0xffff)); uv[1] = bf2f((unsigned short)(u.x >> 16));
    uv[2] = bf2f((unsigned short)(u.y & 0xffff)); uv[3] = bf2f((unsigned short)(u.y >> 16));
    uv[4] = bf2f((unsigned short)(u.z & 0xffff)); uv[5] = bf2f((unsigned short)(u.z >> 16));
    uv[6] = bf2f((unsigned short)(u.w & 0xffff)); uv[7] = bf2f((unsigned short)(u.w >> 16));
    uint4 o;
    o.x = (uint32_t)f2bf(acc[0]) | ((uint32_t)f2bf(acc[1]) << 16);
    o.y = (uint32_t)f2bf(acc[2]) | ((uint32_t)f2bf(acc[3]) << 16);
    o.z = (uint32_t)f2bf(acc[4]) | ((uint32_t)f2bf(acc[5]) << 16);
    o.w = (uint32_t)f2bf(acc[6]) | ((uint32_t)f2bf(acc[7]) << 16);
    *(uint4*)up = o;
    acc[0] = fmaf(p0.x, acc[0], uv[0]);
    acc[1] = fmaf(p0.y, acc[1], uv[1]);
    acc[2] = fmaf(p0.z, acc[2], uv[2]);
    acc[3] = fmaf(p0.w, acc[3], uv[3]);
    acc[4] = fmaf(p1.x, acc[4], uv[4]);
    acc[5] = fmaf(p1.y, acc[5], uv[5]);
    acc[6] = fmaf(p1.z, acc[6], uv[6]);
    acc[7] = fmaf(p1.w, acc[7], uv[7]);
  }
}

// ---------------- scan2: segment replay, J=128 blocks ------------------------------
__global__ __launch_bounds__(512, 2) void scan2(
    const unsigned short* __restrict__ qt, const unsigned short* __restrict__ khT,
    const unsigned short* __restrict__ VT, const float* __restrict__ Af,
    const unsigned short* __restrict__ Sin,
    const unsigned short* __restrict__ numI, const float* __restrict__ invden,
    float* __restrict__ out) {
  __shared__ unsigned short STj[128][520];  // S^T: [j_local][i] bf16, 133 KB
  const int s = blockIdx.x, jt = blockIdx.y, b = blockIdx.z;
  const int lane = threadIdx.x & 63, w = threadIdx.x >> 6;   // wave-uniform w
  const int l16 = lane & 15, q4 = lane >> 4;
  const int j0 = jt * 128;
  const int iw = 128 * (w & 3);   // state i-slice
  const int jw = 64 * (w >> 2);   // state j-slice (relative to j0)
  const int rw = 16 * (w & 3);    // O row-tile
  const int jo = 64 * (w >> 2);   // O j-half (relative to j0)

  f32x4 acc[8][4];

  {
    const size_t pb = ((size_t)b * NSEG + s) * D_DIM;
#pragma unroll
    for (int T = 0; T < 8; ++T)
#pragma unroll
      for (int h = 0; h < 4; ++h) {
        uint2 uu = *(const uint2*)&Sin[(pb + j0 + jw + 16 * h + l16) * (size_t)D_DIM + iw + 16 * T + 4 * q4];
        acc[T][h][0] = bf2f((unsigned short)(uu.x & 0xffff));
        acc[T][h][1] = bf2f((unsigned short)(uu.x >> 16));
        acc[T][h][2] = bf2f((unsigned short)(uu.y & 0xffff));
        acc[T][h][3] = bf2f((unsigned short)(uu.y >> 16));
      }
  }

  for (int cc = 0; cc < CSEG; ++cc) {
    const int c = s * CSEG + cc;
    const size_t cb = ((size_t)b * NCHUNK + c) * D_DIM;
    const size_t t0 = (size_t)b * S_DIM + (size_t)c * CHUNK;
    const size_t ob = cb * CHUNK;

#pragma unroll
    for (int T = 0; T < 8; ++T)
#pragma unroll
      for (int h = 0; h < 4; ++h) {
        uint2 pk;
        pk.x = (uint32_t)f2bf(acc[T][h][0]) | ((uint32_t)f2bf(acc[T][h][1]) << 16);
        pk.y = (uint32_t)f2bf(acc[T][h][2]) | ((uint32_t)f2bf(acc[T][h][3]) << 16);
        *(uint2*)&STj[jw + 16 * h + l16][iw + 16 * T + 4 * q4] = pk;
      }
    __syncthreads();

    {
      f32x4 accO[4];
#pragma unroll
      for (int h = 0; h < 4; ++h) accO[h] = (f32x4){0.f, 0.f, 0.f, 0.f};
#pragma unroll
      for (int ks = 0; ks < 16; ++ks) {
        bf16x8 afr = *(const bf16x8*)&qt[(t0 + rw + l16) * D_DIM + 32 * ks + 8 * q4];
#pragma unroll
        for (int h = 0; h < 4; ++h) {
          bf16x8 bfr = *(const bf16x8*)&STj[jo + 16 * h + l16][32 * ks + 8 * q4];
          accO[h] = __builtin_amdgcn_mfma_f32_16x16x32_bf16(afr, bfr, accO[h], 0, 0, 0);
        }
      }
#pragma unroll
      for (int h = 0; h < 4; ++h)
#pragma unroll
        for (int vv = 0; vv < 4; ++vv) {
          size_t t = t0 + rw + 4 * q4 + vv;
          int j = j0 + jo + 16 * h + l16;
          float idv = invden[t];
          float nI = bf2f(numI[t * D_DIM + j]);
          out[t * D_DIM + j] = (accO[h][vv] + nI) * idv;
        }
    }

    if (cc != CSEG - 1) {
#pragma unroll
      for (int T = 0; T < 8; ++T) {
        float4 af = *(const float4*)&Af[cb + iw + 16 * T + 4 * q4];
#pragma unroll
        for (int h = 0; h < 4; ++h) {
          acc[T][h][0] *= af.x; acc[T][h][1] *= af.y; acc[T][h][2] *= af.z; acc[T][h][3] *= af.w;
        }
      }
      bf16x8 bv0[4], bv1[4];
#pragma unroll
      for (int h = 0; h < 4; ++h) {
        bv0[h] = *(const bf16x8*)&VT[ob + (size_t)(j0 + jw + 16 * h + l16) * CHUNK + 8 * q4];
        bv1[h] = *(const bf16x8*)&VT[ob + (size_t)(j0 + jw + 16 * h + l16) * CHUNK + 32 + 8 * q4];
      }
#pragma unroll
      for (int T = 0; T < 8; ++T) {
        bf16x8 a0 = *(const bf16x8*)&khT[ob + (size_t)(iw + 16 * T + l16) * CHUNK + 8 * q4];
        bf16x8 a1 = *(const bf16x8*)&khT[ob + (size_t)(iw + 16 * T + l16) * CHUNK + 32 + 8 * q4];
#pragma unroll
        for (int h = 0; h < 4; ++h) {
          acc[T][h] = __builtin_amdgcn_mfma_f32_16x16x32_bf16(a0, bv0[h], acc[T][h], 0, 0, 0);
          acc[T][h] = __builtin_amdgcn_mfma_f32_16x16x32_bf16(a1, bv1[h], acc[T][h], 0, 0, 0);
        }
      }
    }
    __syncthreads();
  }
}

// ---------------- launch ----------------
extern "C" void kernel_launch(void* const* d_in, const int* in_sizes, int n_in,
                              void* d_out, int out_size, void* d_ws, size_t ws_size,
                              hipStream_t stream) {
  const float* x  = (const float*)d_in[0];
  const float* Wq = (const float*)d_in[1];
  const float* bq = (const float*)d_in[2];
  const float* Wk = (const float*)d_in[3];
  const float* bk = (const float*)d_in[4];
  const float* Wv = (const float*)d_in[5];
  const float* bv = (const float*)d_in[6];
  const float* Wa = (const float*)d_in[7];
  const float* ba = (const float*)d_in[8];
  float* out = (float*)d_out;

  // Workspace layout identical to R3/R4 (proven): ~172 MB.
  const size_t MD2 = (size_t)M_DIM * D_DIM * 2;
  uint8_t* w = (uint8_t*)d_ws;
  unsigned short* xb   = (unsigned short*)w; w += MD2;
  unsigned short* wb   = (unsigned short*)w; w += (size_t)4 * D_DIM * D_DIM * 2;  // 2 MB
  unsigned short* q_ws = (unsigned short*)w; w += MD2;
  unsigned short* k_ws = (unsigned short*)w; w += MD2;
  unsigned short* v_ws = (unsigned short*)w; w += MD2;
  unsigned short* g_ws = (unsigned short*)w; w += MD2;
  float* Af     = (float*)w; w += (size_t)B_DIM * NCHUNK * D_DIM * 4;  // 1 MB
  float* khs    = (float*)w; w += (size_t)B_DIM * NCHUNK * D_DIM * 4;  // 1 MB
  float* invden = (float*)w; w += (size_t)M_DIM * 4;                   // 128 KB

  unsigned short* qt   = xb;     // xb dead after proj_gemm
  unsigned short* kt   = q_ws;   // same-index overwrite inside prep
  unsigned short* kh   = k_ws;   // same-index overwrite inside prep
  unsigned short* VT   = g_ws;   // g dead after prep
  unsigned short* khT  = v_ws;   // v dead after its transpose
  unsigned short* numI = q_ws;   // kt dead after intra's P-phase
  unsigned short* U    = k_ws;   // kh dead after khT transpose; NSEG*B*512*512*2 == MD2 exactly
  float* zall = (float*)wb;                          // wb dead after proj; 1 MB
  float* Pseg = (float*)((uint8_t*)wb + (1 << 20));  // 128 KB

  cvt_f32_bf16<<<1024, 256, 0, stream>>>(x, xb, M_DIM * D_DIM / 4);
  cvt_f32_bf16<<<128, 256, 0, stream>>>(Wq, wb + 0 * D_DIM * D_DIM, D_DIM * D_DIM / 4);
  cvt_f32_bf16<<<128, 256, 0, stream>>>(Wk, wb + 1 * D_DIM * D_DIM, D_DIM * D_DIM / 4);
  cvt_f32_bf16<<<128, 256, 0, stream>>>(Wv, wb + 2 * D_DIM * D_DIM, D_DIM * D_DIM / 4);
  cvt_f32_bf16<<<128, 256, 0, stream>>>(Wa, wb + 3 * D_DIM * D_DIM, D_DIM * D_DIM / 4);

  proj_gemm<<<dim3(M_DIM / TM, D_DIM / TN, 4), 256, 0, stream>>>(
      xb, wb, bq, bk, bv, ba, q_ws, k_ws, v_ws, g_ws);

  prep<<<dim3(NCHUNK, B_DIM), 512, 0, stream>>>(q_ws, k_ws, g_ws, qt, kt, kh, Af, khs);
  transpose_cd<<<dim3(NCHUNK, B_DIM), 256, 0, stream>>>(v_ws, VT);
  transpose_cd<<<dim3(NCHUNK, B_DIM), 256, 0, stream>>>(kh, khT);
  zscan<<<B_DIM, 512, 0, stream>>>(Af, khs, zall, Pseg);
  intra<<<dim3(NCHUNK, B_DIM), 256, 0, stream>>>(qt, kt, VT, numI, invden);
  denk<<<dim3(NCHUNK, B_DIM), 512, 0, stream>>>(qt, zall, invden);
  useg_k<<<dim3(NSEG, 4, B_DIM), 512, 0, stream>>>(khT, VT, Af, U);
  sscan<<<dim3(128, B_DIM), 256, 0, stream>>>(Pseg, U);   // U -> Sin in place
  scan2<<<dim3(NSEG, 4, B_DIM), 512, 0, stream>>>(qt, khT, VT, Af, U, numI, invden, out);
}

// Round 5
// 505.757 us; speedup vs baseline: 1.4993x; 1.0493x over previous
//
#include <hip/hip_runtime.h>
#include <hip/hip_bf16.h>
#include <cstdint>
#include <cstddef>

#define D_DIM 512
#define B_DIM 8
#define S_DIM 4096
#define M_DIM (B_DIM * S_DIM)   // 32768 tokens
#define CHUNK 64
#define NCHUNK (S_DIM / CHUNK)  // 64 chunks per batch
#define NSEG 8
#define CSEG (NCHUNK / NSEG)    // 8 chunks per segment
#define EPS_C 1e-6f

typedef __attribute__((ext_vector_type(8))) short bf16x8;
typedef __attribute__((ext_vector_type(4))) float f32x4;

#define GLOAD_LDS16(src, dst)                                              \
  __builtin_amdgcn_global_load_lds(                                        \
      (const __attribute__((address_space(1))) void*)(src),                \
      (__attribute__((address_space(3))) void*)(dst), 16, 0, 0)

__device__ __forceinline__ unsigned short f2bf(float f) {
  uint32_t u = __float_as_uint(f);
  u = (u + 0x7fffu + ((u >> 16) & 1u)) >> 16;   // RNE; inputs finite
  return (unsigned short)u;
}
__device__ __forceinline__ float bf2f(unsigned short s) { return __uint_as_float(((uint32_t)s) << 16); }

// ---------------- fp32 -> bf16 conversion ----------------
__global__ void cvt_f32_bf16(const float* __restrict__ in, unsigned short* __restrict__ out, int n4) {
  int i = blockIdx.x * blockDim.x + threadIdx.x;
  int stride = gridDim.x * blockDim.x;
  for (; i < n4; i += stride) {
    float4 f = ((const float4*)in)[i];
    ushort4 o;
    o.x = f2bf(f.x); o.y = f2bf(f.y); o.z = f2bf(f.z); o.w = f2bf(f.w);
    ((ushort4*)out)[i] = o;
  }
}

// ---------------- fused projection GEMM, async global->LDS staging (m97 pattern) ----
// Epilogue: per-wave-private LDS transpose -> bf16x8 coalesced stores (R4-verified).
#define TM 128
#define TN 128
#define BK 32

__global__ __launch_bounds__(256) void proj_gemm(
    const unsigned short* __restrict__ Xb,
    const unsigned short* __restrict__ Wb,
    const float* __restrict__ bq, const float* __restrict__ bk,
    const float* __restrict__ bv, const float* __restrict__ ba,
    unsigned short* __restrict__ q_ws, unsigned short* __restrict__ k_ws,
    unsigned short* __restrict__ v_ws, unsigned short* __restrict__ g_ws) {
  __shared__ unsigned short SB[TM * BK + TN * BK];   // 16 KB (staging; reused by epilogue)
  unsigned short* As = SB;
  unsigned short* Bs = SB + TM * BK;

  const int proj = blockIdx.z;
  const unsigned short* W = Wb + (size_t)proj * D_DIM * D_DIM;
  const int m0 = blockIdx.x * TM;
  const int n0 = blockIdx.y * TN;
  const int tid = threadIdx.x;
  const int lane = tid & 63;
  const int wave = tid >> 6;
  const int wm = (wave & 1) * 64;
  const int wn = (wave >> 1) * 64;
  const int quad = lane >> 4;
  const int l16 = lane & 15;

  f32x4 acc[4][4];
#pragma unroll
  for (int i = 0; i < 4; ++i)
#pragma unroll
    for (int j = 0; j < 4; ++j) acc[i][j] = (f32x4){0.f, 0.f, 0.f, 0.f};

  const int rw = lane >> 2;           // row within 16-row wave slab
  const int kq = (lane & 3) * 8;      // k offset (8 shorts = 16B)

  for (int kc = 0; kc < D_DIM; kc += BK) {
    __syncthreads();  // previous chunk's fragment reads done
    {
      const unsigned short* gA0 = &Xb[(size_t)(m0 + wave * 16 + rw) * D_DIM + kc + kq];
      const unsigned short* gA1 = &Xb[(size_t)(m0 + 64 + wave * 16 + rw) * D_DIM + kc + kq];
      const unsigned short* gB0 = &W[(size_t)(n0 + wave * 16 + rw) * D_DIM + kc + kq];
      const unsigned short* gB1 = &W[(size_t)(n0 + 64 + wave * 16 + rw) * D_DIM + kc + kq];
      GLOAD_LDS16(gA0, &As[(wave * 16) * BK]);
      GLOAD_LDS16(gA1, &As[(64 + wave * 16) * BK]);
      GLOAD_LDS16(gB0, &Bs[(wave * 16) * BK]);
      GLOAD_LDS16(gB1, &Bs[(64 + wave * 16) * BK]);
    }
    __syncthreads();  // barrier drains vmcnt -> staged data visible

    bf16x8 afr[4], bfr[4];
#pragma unroll
    for (int im = 0; im < 4; ++im)
      afr[im] = *(const bf16x8*)&As[(wm + im * 16 + l16) * BK + quad * 8];
#pragma unroll
    for (int in = 0; in < 4; ++in)
      bfr[in] = *(const bf16x8*)&Bs[(wn + in * 16 + l16) * BK + quad * 8];
#pragma unroll
    for (int im = 0; im < 4; ++im)
#pragma unroll
      for (int in = 0; in < 4; ++in)
        acc[im][in] = __builtin_amdgcn_mfma_f32_16x16x32_bf16(afr[im], bfr[in], acc[im][in], 0, 0, 0);
  }

  __syncthreads();   // all fragment reads done before LDS reuse by epilogue

  const float* bias = (proj == 0) ? bq : (proj == 1) ? bk : (proj == 2) ? bv : ba;
  unsigned short* outp = (proj == 0) ? q_ws : (proj == 1) ? k_ws : (proj == 2) ? v_ws : g_ws;
  const bool do_relu = (proj <= 1);
  unsigned short* EP = &SB[wave * 64 * 32];   // per-wave-private 64x32 bf16 (4 KB)

#pragma unroll
  for (int p = 0; p < 2; ++p) {   // column halves of the wave's 64x64 tile
#pragma unroll
    for (int half = 0; half < 2; ++half) {
      const int in = 2 * p + half;
      const int nn = n0 + wn + in * 16 + l16;
      const float bn = bias[nn];
#pragma unroll
      for (int im = 0; im < 4; ++im) {
#pragma unroll
        for (int vv = 0; vv < 4; ++vv) {
          float val = acc[im][in][vv] + bn;
          if (do_relu) val = fmaxf(val, 0.f);
          EP[(im * 16 + quad * 4 + vv) * 32 + half * 16 + l16] = f2bf(val);
        }
      }
    }
#pragma unroll
    for (int it = 0; it < 4; ++it) {
      const int row = it * 16 + (lane >> 2);
      const int ccol = (lane & 3) * 8;
      bf16x8 vdat = *(const bf16x8*)&EP[row * 32 + ccol];
      size_t gidx = (size_t)(m0 + wm + row) * D_DIM + (size_t)(n0 + wn + p * 32 + ccol);
      *(bf16x8*)&outp[gidx] = vdat;
    }
  }
}

// ---------------- prep: cum-factorized operands, segmented + bf16x8-vectorized -----
__global__ __launch_bounds__(512) void prep(
    const unsigned short* __restrict__ q, const unsigned short* __restrict__ k,
    const unsigned short* __restrict__ g,
    unsigned short* __restrict__ qt, unsigned short* __restrict__ kt,
    unsigned short* __restrict__ kh,
    float* __restrict__ Af, float* __restrict__ khs) {
  __shared__ float segp[8][512];   // 16 KB
  const int c = blockIdx.x, b = blockIdx.y;
  const int seg = threadIdx.x >> 6;   // 8 segments x 8 rows
  const int t = threadIdx.x & 63;
  const int i0 = t * 8;               // 8 cols per thread
  const int r0 = seg * 8;
  const size_t t0 = (size_t)b * S_DIM + (size_t)c * CHUNK;
  const size_t cb = ((size_t)b * NCHUNK + c) * D_DIM;

  float sp[8];
#pragma unroll
  for (int j = 0; j < 8; ++j) sp[j] = 1.f;
  for (int r = 0; r < 8; ++r) {
    bf16x8 gv = *(const bf16x8*)&g[(t0 + r0 + r) * D_DIM + i0];
#pragma unroll
    for (int j = 0; j < 8; ++j)
      sp[j] *= 1.f / (1.f + __expf(-bf2f((unsigned short)gv[j])));
  }
  *(float4*)&segp[seg][i0] = *(float4*)&sp[0];
  *(float4*)&segp[seg][i0 + 4] = *(float4*)&sp[4];
  __syncthreads();

  float pre[8], tot[8];
#pragma unroll
  for (int j = 0; j < 8; ++j) { pre[j] = 1.f; tot[j] = 1.f; }
  for (int s2 = 0; s2 < 8; ++s2) {
    float4 v0 = *(const float4*)&segp[s2][i0];
    float4 v1 = *(const float4*)&segp[s2][i0 + 4];
    float v[8] = {v0.x, v0.y, v0.z, v0.w, v1.x, v1.y, v1.z, v1.w};
#pragma unroll
    for (int j = 0; j < 8; ++j) {
      tot[j] *= v[j];
      if (s2 < seg) pre[j] *= v[j];
    }
  }
  if (seg == 0) {
    float4 a0 = {tot[0], tot[1], tot[2], tot[3]};
    float4 a1 = {tot[4], tot[5], tot[6], tot[7]};
    *(float4*)&Af[cb + i0] = a0;
    *(float4*)&Af[cb + i0 + 4] = a1;
  }

  float cum[8], ssum[8];
#pragma unroll
  for (int j = 0; j < 8; ++j) { cum[j] = pre[j]; ssum[j] = 0.f; }
  for (int r = 0; r < 8; ++r) {
    size_t idx = (t0 + r0 + r) * D_DIM + i0;
    bf16x8 gv = *(const bf16x8*)&g[idx];
    bf16x8 qv8 = *(const bf16x8*)&q[idx];
    bf16x8 kv8 = *(const bf16x8*)&k[idx];
    bf16x8 oq, ok, okh;
#pragma unroll
    for (int j = 0; j < 8; ++j) {
      cum[j] *= 1.f / (1.f + __expf(-bf2f((unsigned short)gv[j])));
      float qv = bf2f((unsigned short)qv8[j]);
      float kv = bf2f((unsigned short)kv8[j]);
      oq[j] = (short)f2bf(qv * cum[j]);
      float inv = 1.f / cum[j];
      ok[j] = (short)f2bf(kv * inv);
      float khf = kv * (tot[j] * inv);
      okh[j] = (short)f2bf(khf);
      ssum[j] += khf;
    }
    *(bf16x8*)&qt[idx] = oq;
    *(bf16x8*)&kt[idx] = ok;
    *(bf16x8*)&kh[idx] = okh;
  }

  __syncthreads();
  *(float4*)&segp[seg][i0] = *(float4*)&ssum[0];
  *(float4*)&segp[seg][i0 + 4] = *(float4*)&ssum[4];
  __syncthreads();
  if (seg == 0) {
    float s[8];
#pragma unroll
    for (int j = 0; j < 8; ++j) s[j] = 0.f;
    for (int s2 = 0; s2 < 8; ++s2) {
      float4 v0 = *(const float4*)&segp[s2][i0];
      float4 v1 = *(const float4*)&segp[s2][i0 + 4];
      s[0] += v0.x; s[1] += v0.y; s[2] += v0.z; s[3] += v0.w;
      s[4] += v1.x; s[5] += v1.y; s[6] += v1.z; s[7] += v1.w;
    }
    float4 a0 = {s[0], s[1], s[2], s[3]};
    float4 a1 = {s[4], s[5], s[6], s[7]};
    *(float4*)&khs[cb + i0] = a0;
    *(float4*)&khs[cb + i0 + 4] = a1;
  }
}

// ---------------- per-chunk transpose [r][i] -> [i][r] (verified R3) ----------------
__global__ __launch_bounds__(256) void transpose_cd(
    const unsigned short* __restrict__ in, unsigned short* __restrict__ outT) {
  __shared__ unsigned short tile[CHUNK][264];
  const int c = blockIdx.x, b = blockIdx.y;
  const size_t base_in = ((size_t)b * S_DIM + (size_t)c * CHUNK) * D_DIM;
  const size_t base_out = ((size_t)b * NCHUNK + c) * (size_t)D_DIM * CHUNK;
  const int tid = threadIdx.x;
#pragma unroll
  for (int h = 0; h < 2; ++h) {
    if (h) __syncthreads();
#pragma unroll
    for (int it = 0; it < 8; ++it) {
      int flat = (it * 256 + tid) * 8;
      int row = flat >> 8;
      int col = flat & 255;
      *(uint4*)&tile[row][col] = *(const uint4*)&in[base_in + (size_t)row * D_DIM + h * 256 + col];
    }
    __syncthreads();
#pragma unroll
    for (int it = 0; it < 8; ++it) {
      int wq = it * 256 + tid;
      int i_loc = wq >> 3;
      int r0 = (wq & 7) * 8;
      ushort4 v0, v1;
      v0.x = tile[r0 + 0][i_loc]; v0.y = tile[r0 + 1][i_loc];
      v0.z = tile[r0 + 2][i_loc]; v0.w = tile[r0 + 3][i_loc];
      v1.x = tile[r0 + 4][i_loc]; v1.y = tile[r0 + 5][i_loc];
      v1.z = tile[r0 + 6][i_loc]; v1.w = tile[r0 + 7][i_loc];
      size_t o = base_out + (size_t)(h * 256 + i_loc) * CHUNK + r0;
      *(ushort4*)&outT[o] = v0;
      *(ushort4*)&outT[o + 4] = v1;
    }
  }
}

// ---------------- intra-chunk: P = mask(qt·kt^T), rowsums, numI = P·V (verified R3) ----
__global__ __launch_bounds__(256) void intra(
    const unsigned short* __restrict__ qt, const unsigned short* kt,
    const unsigned short* __restrict__ VT,
    unsigned short* numI, float* __restrict__ rs) {
  __shared__ unsigned short P_lds[CHUNK][CHUNK + 8];
  const int c = blockIdx.x, b = blockIdx.y;
  const size_t t0 = (size_t)b * S_DIM + (size_t)c * CHUNK;
  const int lane = threadIdx.x & 63, w = threadIdx.x >> 6;
  const int l16 = lane & 15, q4 = lane >> 4;

  f32x4 accP[4];
#pragma unroll
  for (int n = 0; n < 4; ++n) accP[n] = (f32x4){0.f, 0.f, 0.f, 0.f};
#pragma unroll
  for (int ks = 0; ks < 16; ++ks) {
    bf16x8 afr = *(const bf16x8*)&qt[(t0 + 16 * w + l16) * D_DIM + 32 * ks + 8 * q4];
#pragma unroll
    for (int n = 0; n < 4; ++n) {
      bf16x8 bfr = *(const bf16x8*)&kt[(t0 + 16 * n + l16) * D_DIM + 32 * ks + 8 * q4];
      accP[n] = __builtin_amdgcn_mfma_f32_16x16x32_bf16(afr, bfr, accP[n], 0, 0, 0);
    }
  }
  float rsum[4] = {0.f, 0.f, 0.f, 0.f};
#pragma unroll
  for (int n = 0; n < 4; ++n) {
    int m = 16 * n + l16;
#pragma unroll
    for (int vv = 0; vv < 4; ++vv) {
      int r = 16 * w + 4 * q4 + vv;
      float pv = (m <= r) ? accP[n][vv] : 0.f;
      rsum[vv] += pv;
      P_lds[r][m] = f2bf(pv);
    }
  }
#pragma unroll
  for (int msk = 1; msk < 16; msk <<= 1) {
#pragma unroll
    for (int vv = 0; vv < 4; ++vv) rsum[vv] += __shfl_xor(rsum[vv], msk, 64);
  }
  if (l16 == 0) {
#pragma unroll
    for (int vv = 0; vv < 4; ++vv) rs[t0 + 16 * w + 4 * q4 + vv] = rsum[vv];
  }
  __syncthreads();
  bf16x8 pa0 = *(const bf16x8*)&P_lds[16 * w + l16][8 * q4];
  bf16x8 pa1 = *(const bf16x8*)&P_lds[16 * w + l16][32 + 8 * q4];
  const size_t vtb = ((size_t)b * NCHUNK + c) * (size_t)D_DIM * CHUNK;
#pragma unroll 4
  for (int nt = 0; nt < 32; ++nt) {
    bf16x8 b0 = *(const bf16x8*)&VT[vtb + (size_t)(nt * 16 + l16) * CHUNK + 8 * q4];
    bf16x8 b1 = *(const bf16x8*)&VT[vtb + (size_t)(nt * 16 + l16) * CHUNK + 32 + 8 * q4];
    f32x4 acc = (f32x4){0.f, 0.f, 0.f, 0.f};
    acc = __builtin_amdgcn_mfma_f32_16x16x32_bf16(pa0, b0, acc, 0, 0, 0);
    acc = __builtin_amdgcn_mfma_f32_16x16x32_bf16(pa1, b1, acc, 0, 0, 0);
#pragma unroll
    for (int vv = 0; vv < 4; ++vv)
      numI[(t0 + 16 * w + 4 * q4 + vv) * D_DIM + nt * 16 + l16] = f2bf(acc[vv]);
  }
}

// ---------------- zscan: barrier-free z recurrence; also Pseg gate products ----------
__global__ __launch_bounds__(512) void zscan(
    const float* __restrict__ Af, const float* __restrict__ khs,
    float* __restrict__ zall, float* __restrict__ Pseg) {
  const int b = blockIdx.x;
  const int i = threadIdx.x;
  float z = 0.f, rp = 1.f;
  for (int c = 0; c < NCHUNK; ++c) {
    const size_t cb = ((size_t)b * NCHUNK + c) * D_DIM;
    zall[cb + i] = z;
    float af = Af[cb + i];
    z = fmaf(af, z, khs[cb + i]);
    rp *= af;
    if ((c & (CSEG - 1)) == CSEG - 1) {
      Pseg[((size_t)b * NSEG + (c / CSEG)) * D_DIM + i] = rp;
      rp = 1.f;
    }
  }
}

// ---------------- denk: fully parallel denominators (verified R4) ------------------
__global__ __launch_bounds__(512) void denk(
    const unsigned short* __restrict__ qt, const float* __restrict__ zall,
    float* rs_invden) {
  const int c = blockIdx.x, b = blockIdx.y;
  const int lane = threadIdx.x & 63, w = threadIdx.x >> 6;
  const size_t t0 = (size_t)b * S_DIM + (size_t)c * CHUNK;
  const size_t zb = ((size_t)b * NCHUNK + c) * D_DIM;
  float4 z0 = *(const float4*)&zall[zb + lane * 8];
  float4 z1 = *(const float4*)&zall[zb + lane * 8 + 4];
#pragma unroll
  for (int rr = 0; rr < 8; ++rr) {
    int r = 8 * w + rr;
    bf16x8 qv = *(const bf16x8*)&qt[(t0 + r) * D_DIM + lane * 8];
    float p = 0.f;
    p = fmaf(bf2f((unsigned short)qv[0]), z0.x, p);
    p = fmaf(bf2f((unsigned short)qv[1]), z0.y, p);
    p = fmaf(bf2f((unsigned short)qv[2]), z0.z, p);
    p = fmaf(bf2f((unsigned short)qv[3]), z0.w, p);
    p = fmaf(bf2f((unsigned short)qv[4]), z1.x, p);
    p = fmaf(bf2f((unsigned short)qv[5]), z1.y, p);
    p = fmaf(bf2f((unsigned short)qv[6]), z1.z, p);
    p = fmaf(bf2f((unsigned short)qv[7]), z1.w, p);
#pragma unroll
    for (int msk = 1; msk < 64; msk <<= 1) p += __shfl_xor(p, msk, 64);
    if (lane == 0) {
      float* iv = &rs_invden[t0 + r];
      *iv = 1.f / (p + *iv + EPS_C);
    }
  }
}

// ---------------- useg: per-segment state contribution, J=128 blocks ----------------
// NEW: 8 i-slices x full-j wave decomposition (khT unique per wave, no 2x redundancy)
// + VT staged to LDS via global_load_lds (was 4x redundant reg loads), double-buffered,
// pre-swizzled source (m173) so swizzled ds_reads are bank-uniform.
__global__ __launch_bounds__(512, 2) void useg_k(
    const unsigned short* __restrict__ khT, const unsigned short* __restrict__ VT,
    const float* __restrict__ Af, unsigned short* __restrict__ U) {
  __shared__ unsigned short VTl[2][128 * 64];   // 32 KB dbuf, swizzled image
  const int s = blockIdx.x, jt = blockIdx.y, b = blockIdx.z;
  const int lane = threadIdx.x & 63, w = threadIdx.x >> 6;
  const int l16 = lane & 15, q4 = lane >> 4;
  const int j0 = jt * 128;
  const int iw = 64 * w;                       // i-slice per wave
  const int vrow = lane >> 3;                  // row within 8-row stage group
  const int vswz = (lane & 7) ^ (vrow & 7);    // swizzled source slot

  f32x4 acc[4][8];
#pragma unroll
  for (int T = 0; T < 4; ++T)
#pragma unroll
    for (int h = 0; h < 8; ++h) acc[T][h] = (f32x4){0.f, 0.f, 0.f, 0.f};

  const size_t cb0 = ((size_t)b * NCHUNK + s * CSEG) * D_DIM;
  // prologue: stage VT(0), load khT(0) fragments
  {
    const size_t ob0 = cb0 * CHUNK;
#pragma unroll
    for (int kk = 0; kk < 2; ++kk) {
      const int k = 2 * w + kk;
      GLOAD_LDS16(&VT[ob0 + (size_t)(j0 + 8 * k + vrow) * CHUNK + vswz * 8],
                  &VTl[0][k * 512]);
    }
  }
  bf16x8 a0[4], a1[4];
  {
    const size_t ob0 = cb0 * CHUNK;
#pragma unroll
    for (int T = 0; T < 4; ++T) {
      a0[T] = *(const bf16x8*)&khT[ob0 + (size_t)(iw + 16 * T + l16) * CHUNK + 8 * q4];
      a1[T] = *(const bf16x8*)&khT[ob0 + (size_t)(iw + 16 * T + l16) * CHUNK + 32 + 8 * q4];
    }
  }

  for (int cc = 0; cc < CSEG; ++cc) {
    const size_t cb = cb0 + (size_t)cc * D_DIM;
    __syncthreads();   // VT(cc) staged (barrier drains vmcnt); khT(cc) also arrived
    if (cc + 1 < CSEG) {
      const size_t obn = (cb + D_DIM) * CHUNK;
#pragma unroll
      for (int kk = 0; kk < 2; ++kk) {
        const int k = 2 * w + kk;
        GLOAD_LDS16(&VT[obn + (size_t)(j0 + 8 * k + vrow) * CHUNK + vswz * 8],
                    &VTl[(cc + 1) & 1][k * 512]);
      }
    }
#pragma unroll
    for (int T = 0; T < 4; ++T) {
      float4 af = *(const float4*)&Af[cb + iw + 16 * T + 4 * q4];
#pragma unroll
      for (int h = 0; h < 8; ++h) {
        acc[T][h][0] *= af.x; acc[T][h][1] *= af.y; acc[T][h][2] *= af.z; acc[T][h][3] *= af.w;
      }
    }
    const unsigned short* Vb = VTl[cc & 1];
#pragma unroll
    for (int h = 0; h < 8; ++h) {
      const int jpos = 16 * h + l16;
      const int swz = jpos & 7;
      bf16x8 bv0 = *(const bf16x8*)&Vb[jpos * 64 + ((q4 ^ swz) * 8)];
      bf16x8 bv1 = *(const bf16x8*)&Vb[jpos * 64 + (((4 + q4) ^ swz) * 8)];
#pragma unroll
      for (int T = 0; T < 4; ++T) {
        acc[T][h] = __builtin_amdgcn_mfma_f32_16x16x32_bf16(a0[T], bv0, acc[T][h], 0, 0, 0);
        acc[T][h] = __builtin_amdgcn_mfma_f32_16x16x32_bf16(a1[T], bv1, acc[T][h], 0, 0, 0);
      }
    }
    if (cc + 1 < CSEG) {   // issue next khT after last use of a0/a1
      const size_t obn = (cb + D_DIM) * CHUNK;
#pragma unroll
      for (int T = 0; T < 4; ++T) {
        a0[T] = *(const bf16x8*)&khT[obn + (size_t)(iw + 16 * T + l16) * CHUNK + 8 * q4];
        a1[T] = *(const bf16x8*)&khT[obn + (size_t)(iw + 16 * T + l16) * CHUNK + 32 + 8 * q4];
      }
    }
  }
  const size_t ub = ((size_t)b * NSEG + s) * D_DIM;
#pragma unroll
  for (int T = 0; T < 4; ++T)
#pragma unroll
    for (int h = 0; h < 8; ++h) {
      uint2 pk;
      pk.x = (uint32_t)f2bf(acc[T][h][0]) | ((uint32_t)f2bf(acc[T][h][1]) << 16);
      pk.y = (uint32_t)f2bf(acc[T][h][2]) | ((uint32_t)f2bf(acc[T][h][3]) << 16);
      *(uint2*)&U[(ub + j0 + 16 * h + l16) * (size_t)D_DIM + iw + 16 * T + 4 * q4] = pk;
    }
}

// ---------------- sscan: in-place prefix over segments: U[s] -> Sin[s] -------------
__global__ __launch_bounds__(256) void sscan(
    const float* __restrict__ Pseg, unsigned short* __restrict__ U) {
  const int b = blockIdx.y;
  const int flat = blockIdx.x * 256 + threadIdx.x;   // 0 .. 32767
  const int j = flat >> 6;
  const int i0 = (flat & 63) * 8;
  float acc[8];
#pragma unroll
  for (int t = 0; t < 8; ++t) acc[t] = 0.f;
  for (int s = 0; s < NSEG; ++s) {
    const size_t pb = ((size_t)b * NSEG + s) * D_DIM;
    unsigned short* up = &U[(pb + j) * (size_t)D_DIM + i0];
    uint4 u = *(const uint4*)up;
    float4 p0 = *(const float4*)&Pseg[pb + i0];
    float4 p1 = *(const float4*)&Pseg[pb + i0 + 4];
    float uv[8];
    uv[0] = bf2f((unsigned short)(u.x & 0xffff)); uv[1] = bf2f((unsigned short)(u.x >> 16));
    uv[2] = bf2f((unsigned short)(u.y & 0xffff)); uv[3] = bf2f((unsigned short)(u.y >> 16));
    uv[4] = bf2f((unsigned short)(u.z & 0xffff)); uv[5] = bf2f((unsigned short)(u.z >> 16));
    uv[6] = bf2f((unsigned short)(u.w & 0xffff)); uv[7] = bf2f((unsigned short)(u.w >> 16));
    uint4 o;
    o.x = (uint32_t)f2bf(acc[0]) | ((uint32_t)f2bf(acc[1]) << 16);
    o.y = (uint32_t)f2bf(acc[2]) | ((uint32_t)f2bf(acc[3]) << 16);
    o.z = (uint32_t)f2bf(acc[4]) | ((uint32_t)f2bf(acc[5]) << 16);
    o.w = (uint32_t)f2bf(acc[6]) | ((uint32_t)f2bf(acc[7]) << 16);
    *(uint4*)up = o;
    acc[0] = fmaf(p0.x, acc[0], uv[0]);
    acc[1] = fmaf(p0.y, acc[1], uv[1]);
    acc[2] = fmaf(p0.z, acc[2], uv[2]);
    acc[3] = fmaf(p0.w, acc[3], uv[3]);
    acc[4] = fmaf(p1.x, acc[4], uv[4]);
    acc[5] = fmaf(p1.y, acc[5], uv[5]);
    acc[6] = fmaf(p1.z, acc[6], uv[6]);
    acc[7] = fmaf(p1.w, acc[7], uv[7]);
  }
}

// ---------------- scan2: segment replay, J=128 blocks ------------------------------
// NEW: state decomp 8 i-slices x full-j (khT unique/wave: 128->64 KB/chunk requests);
// VT via LDS (global_load_lds + swizzle, 64->16 KB/chunk); khT/VT issued at top of
// chunk (T14 early-issue: latency hidden under STj staging + barrier).
__global__ __launch_bounds__(512, 2) void scan2(
    const unsigned short* __restrict__ qt, const unsigned short* __restrict__ khT,
    const unsigned short* __restrict__ VT, const float* __restrict__ Af,
    const unsigned short* __restrict__ Sin,
    const unsigned short* __restrict__ numI, const float* __restrict__ invden,
    float* __restrict__ out) {
  __shared__ unsigned short STj[128][520];   // S^T: [j_local][i] bf16, 133 KB
  __shared__ unsigned short VTl[128 * 64];   // 16 KB, swizzled image
  const int s = blockIdx.x, jt = blockIdx.y, b = blockIdx.z;
  const int lane = threadIdx.x & 63, w = threadIdx.x >> 6;   // wave-uniform w
  const int l16 = lane & 15, q4 = lane >> 4;
  const int j0 = jt * 128;
  const int iw = 64 * w;          // state i-slice (unique per wave)
  const int rw = 16 * (w & 3);    // O row-tile
  const int jo = 64 * (w >> 2);   // O j-half
  const int vrow = lane >> 3;
  const int vswz = (lane & 7) ^ (vrow & 7);

  f32x4 acc[4][8];

  // initial state for this segment (precomputed by sscan)
  {
    const size_t pb = ((size_t)b * NSEG + s) * D_DIM;
#pragma unroll
    for (int T = 0; T < 4; ++T)
#pragma unroll
      for (int h = 0; h < 8; ++h) {
        uint2 uu = *(const uint2*)&Sin[(pb + j0 + 16 * h + l16) * (size_t)D_DIM + iw + 16 * T + 4 * q4];
        acc[T][h][0] = bf2f((unsigned short)(uu.x & 0xffff));
        acc[T][h][1] = bf2f((unsigned short)(uu.x >> 16));
        acc[T][h][2] = bf2f((unsigned short)(uu.y & 0xffff));
        acc[T][h][3] = bf2f((unsigned short)(uu.y >> 16));
      }
  }

  for (int cc = 0; cc < CSEG; ++cc) {
    const int c = s * CSEG + cc;
    const size_t cb = ((size_t)b * NCHUNK + c) * D_DIM;
    const size_t t0 = (size_t)b * S_DIM + (size_t)c * CHUNK;
    const size_t ob = cb * CHUNK;
    const bool upd = (cc != CSEG - 1);

    // early-issue: VT -> LDS, khT -> regs (consumed in state phase, after O)
    bf16x8 a0[4], a1[4];
    if (upd) {
#pragma unroll
      for (int kk = 0; kk < 2; ++kk) {
        const int k = 2 * w + kk;
        GLOAD_LDS16(&VT[ob + (size_t)(j0 + 8 * k + vrow) * CHUNK + vswz * 8],
                    &VTl[k * 512]);
      }
#pragma unroll
      for (int T = 0; T < 4; ++T) {
        a0[T] = *(const bf16x8*)&khT[ob + (size_t)(iw + 16 * T + l16) * CHUNK + 8 * q4];
        a1[T] = *(const bf16x8*)&khT[ob + (size_t)(iw + 16 * T + l16) * CHUNK + 32 + 8 * q4];
      }
    }

    // stage pre-update S^T to LDS (each wave its i-slice, full j)
#pragma unroll
    for (int T = 0; T < 4; ++T)
#pragma unroll
      for (int h = 0; h < 8; ++h) {
        uint2 pk;
        pk.x = (uint32_t)f2bf(acc[T][h][0]) | ((uint32_t)f2bf(acc[T][h][1]) << 16);
        pk.y = (uint32_t)f2bf(acc[T][h][2]) | ((uint32_t)f2bf(acc[T][h][3]) << 16);
        *(uint2*)&STj[16 * h + l16][iw + 16 * T + 4 * q4] = pk;
      }
    __syncthreads();   // STj + VTl staged, khT arrived

    // O-compute: out rows [rw,rw+16) x cols [j0+jo, j0+jo+64)
    {
      f32x4 accO[4];
#pragma unroll
      for (int h = 0; h < 4; ++h) accO[h] = (f32x4){0.f, 0.f, 0.f, 0.f};
#pragma unroll
      for (int ks = 0; ks < 16; ++ks) {
        bf16x8 afr = *(const bf16x8*)&qt[(t0 + rw + l16) * D_DIM + 32 * ks + 8 * q4];
#pragma unroll
        for (int h = 0; h < 4; ++h) {
          bf16x8 bfr = *(const bf16x8*)&STj[jo + 16 * h + l16][32 * ks + 8 * q4];
          accO[h] = __builtin_amdgcn_mfma_f32_16x16x32_bf16(afr, bfr, accO[h], 0, 0, 0);
        }
      }
#pragma unroll
      for (int h = 0; h < 4; ++h)
#pragma unroll
        for (int vv = 0; vv < 4; ++vv) {
          size_t t = t0 + rw + 4 * q4 + vv;
          int j = j0 + jo + 16 * h + l16;
          float idv = invden[t];
          float nI = bf2f(numI[t * D_DIM + j]);
          out[t * D_DIM + j] = (accO[h][vv] + nI) * idv;
        }
    }

    // state update (skip on last chunk)
    if (upd) {
#pragma unroll
      for (int T = 0; T < 4; ++T) {
        float4 af = *(const float4*)&Af[cb + iw + 16 * T + 4 * q4];
#pragma unroll
        for (int h = 0; h < 8; ++h) {
          acc[T][h][0] *= af.x; acc[T][h][1] *= af.y; acc[T][h][2] *= af.z; acc[T][h][3] *= af.w;
        }
      }
#pragma unroll
      for (int h = 0; h < 8; ++h) {
        const int jpos = 16 * h + l16;
        const int swz = jpos & 7;
        bf16x8 bv0 = *(const bf16x8*)&VTl[jpos * 64 + ((q4 ^ swz) * 8)];
        bf16x8 bv1 = *(const bf16x8*)&VTl[jpos * 64 + (((4 + q4) ^ swz) * 8)];
#pragma unroll
        for (int T = 0; T < 4; ++T) {
          acc[T][h] = __builtin_amdgcn_mfma_f32_16x16x32_bf16(a0[T], bv0, acc[T][h], 0, 0, 0);
          acc[T][h] = __builtin_amdgcn_mfma_f32_16x16x32_bf16(a1[T], bv1, acc[T][h], 0, 0, 0);
        }
      }
    }
    __syncthreads();   // protect STj/VTl before next chunk's staging
  }
}

// ---------------- launch ----------------
extern "C" void kernel_launch(void* const* d_in, const int* in_sizes, int n_in,
                              void* d_out, int out_size, void* d_ws, size_t ws_size,
                              hipStream_t stream) {
  const float* x  = (const float*)d_in[0];
  const float* Wq = (const float*)d_in[1];
  const float* bq = (const float*)d_in[2];
  const float* Wk = (const float*)d_in[3];
  const float* bk = (const float*)d_in[4];
  const float* Wv = (const float*)d_in[5];
  const float* bv = (const float*)d_in[6];
  const float* Wa = (const float*)d_in[7];
  const float* ba = (const float*)d_in[8];
  float* out = (float*)d_out;

  // Workspace layout identical to R3/R4 (proven): ~172 MB.
  const size_t MD2 = (size_t)M_DIM * D_DIM * 2;
  uint8_t* w = (uint8_t*)d_ws;
  unsigned short* xb   = (unsigned short*)w; w += MD2;
  unsigned short* wb   = (unsigned short*)w; w += (size_t)4 * D_DIM * D_DIM * 2;  // 2 MB
  unsigned short* q_ws = (unsigned short*)w; w += MD2;
  unsigned short* k_ws = (unsigned short*)w; w += MD2;
  unsigned short* v_ws = (unsigned short*)w; w += MD2;
  unsigned short* g_ws = (unsigned short*)w; w += MD2;
  float* Af     = (float*)w; w += (size_t)B_DIM * NCHUNK * D_DIM * 4;  // 1 MB
  float* khs    = (float*)w; w += (size_t)B_DIM * NCHUNK * D_DIM * 4;  // 1 MB
  float* invden = (float*)w; w += (size_t)M_DIM * 4;                   // 128 KB

  unsigned short* qt   = xb;     // xb dead after proj_gemm
  unsigned short* kt   = q_ws;   // same-index overwrite inside prep
  unsigned short* kh   = k_ws;   // same-index overwrite inside prep
  unsigned short* VT   = g_ws;   // g dead after prep
  unsigned short* khT  = v_ws;   // v dead after its transpose
  unsigned short* numI = q_ws;   // kt dead after intra's P-phase
  unsigned short* U    = k_ws;   // kh dead after khT transpose; NSEG*B*512*512*2 == MD2 exactly
  float* zall = (float*)wb;                          // wb dead after proj; 1 MB
  float* Pseg = (float*)((uint8_t*)wb + (1 << 20));  // 128 KB

  cvt_f32_bf16<<<1024, 256, 0, stream>>>(x, xb, M_DIM * D_DIM / 4);
  cvt_f32_bf16<<<128, 256, 0, stream>>>(Wq, wb + 0 * D_DIM * D_DIM, D_DIM * D_DIM / 4);
  cvt_f32_bf16<<<128, 256, 0, stream>>>(Wk, wb + 1 * D_DIM * D_DIM, D_DIM * D_DIM / 4);
  cvt_f32_bf16<<<128, 256, 0, stream>>>(Wv, wb + 2 * D_DIM * D_DIM, D_DIM * D_DIM / 4);
  cvt_f32_bf16<<<128, 256, 0, stream>>>(Wa, wb + 3 * D_DIM * D_DIM, D_DIM * D_DIM / 4);

  proj_gemm<<<dim3(M_DIM / TM, D_DIM / TN, 4), 256, 0, stream>>>(
      xb, wb, bq, bk, bv, ba, q_ws, k_ws, v_ws, g_ws);

  prep<<<dim3(NCHUNK, B_DIM), 512, 0, stream>>>(q_ws, k_ws, g_ws, qt, kt, kh, Af, khs);
  transpose_cd<<<dim3(NCHUNK, B_DIM), 256, 0, stream>>>(v_ws, VT);
  transpose_cd<<<dim3(NCHUNK, B_DIM), 256, 0, stream>>>(kh, khT);
  zscan<<<B_DIM, 512, 0, stream>>>(Af, khs, zall, Pseg);
  intra<<<dim3(NCHUNK, B_DIM), 256, 0, stream>>>(qt, kt, VT, numI, invden);
  denk<<<dim3(NCHUNK, B_DIM), 512, 0, stream>>>(qt, zall, invden);
  useg_k<<<dim3(NSEG, 4, B_DIM), 512, 0, stream>>>(khT, VT, Af, U);
  sscan<<<dim3(128, B_DIM), 256, 0, stream>>>(Pseg, U);   // U -> Sin in place
  scan2<<<dim3(NSEG, 4, B_DIM), 512, 0, stream>>>(qt, khT, VT, Af, U, numI, invden, out);
}